// Round 4
// baseline (287.444 us; speedup 1.0000x reference)
//
#include <hip/hip_runtime.h>

#define TPB 256

using half8  = __attribute__((ext_vector_type(8))) _Float16;
using fp16x2 = __attribute__((ext_vector_type(2))) __fp16;
using f32x4  = __attribute__((ext_vector_type(4))) float;

static __device__ __forceinline__ unsigned short h2u(_Float16 h) {
    union { _Float16 h; unsigned short u; } v; v.h = h; return v.u;
}
static __device__ __forceinline__ unsigned pkrtz(float a, float b) {
    fp16x2 h = __builtin_amdgcn_cvt_pkrtz(a, b);
    return __builtin_bit_cast(unsigned, h);
}
template <int CTRL>
static __device__ __forceinline__ float dppmov(float x) {
    return __int_as_float(__builtin_amdgcn_mov_dpp(__float_as_int(x), CTRL, 0xF, 0xF, true));
}
#define DPP_SWAP 0xB1   // quad_perm [1,0,3,2]

// ---------- fused kernel: prep phase -> software grid barrier -> MFMA MLP phase ----------
__global__ __launch_bounds__(TPB) void k_fused(const float* __restrict__ x,
                                               const float* __restrict__ h_dag,
                                               const float* __restrict__ h_glob,
                                               const int* __restrict__ ptr,
                                               const int* __restrict__ job_indices,
                                               const int* __restrict__ num_exec_acts,
                                               const float* __restrict__ W1,
                                               const float* __restrict__ b1,
                                               const float* __restrict__ W2,
                                               const float* __restrict__ b2,
                                               const float* __restrict__ W3,
                                               const float* __restrict__ b3,
                                               const float* __restrict__ W4,
                                               const float* __restrict__ b4,
                                               unsigned int* __restrict__ feat,
                                               int* __restrict__ bsum,
                                               int* __restrict__ jsv,
                                               uint4* __restrict__ wfrag,
                                               float4* __restrict__ bfrag,
                                               float* __restrict__ out,
                                               int* bar,
                                               int J, int nb, int T, int numTiles)
{
    __shared__ __align__(16) char smem[4 * 4096];   // one 4 KB slab per wave (MLP phase)
    __shared__ int boffs[TPB];                       // prep scan buffer, then exclusive scan of bsum
    __shared__ int swin[4][64];                      // per-wave job-start window
    __shared__ int srow[4][32];                      // per-wave per-row (job<<8|exec)
    const int tid  = threadIdx.x;
    const int lane = tid & 63;
    const int wv   = tid >> 6;
    const int n    = lane & 15;
    const int q    = lane >> 4;
    char* slab = smem + wv * 4096;

    // ================= PHASE A: prep (grid-stride over nb chunks + 1 wfrag chunk) =================
    for (int c = blockIdx.x; c <= nb; c += gridDim.x) {
        if (c == nb) {
            if (tid < 64) {
                int l2 = tid;
                int nn = l2 & 15, qq = l2 >> 4;
#pragma unroll
                for (int nt = 0; nt < 4; nt++) {
#pragma unroll
                    for (int s = 0; s < 2; s++) {
                        half8 w1f, w2f;
#pragma unroll
                        for (int jj = 0; jj < 8; jj++) {
                            int ks = s * 32 + qq * 8 + jj;
                            w1f[jj] = (ks < 36) ? (_Float16)W1[ks * 64 + nt * 16 + nn] : (_Float16)0.0f;
                            w2f[jj] = (_Float16)W2[ks * 64 + nt * 16 + nn];
                        }
                        wfrag[(nt * 2 + s) * 64 + l2]     = __builtin_bit_cast(uint4, w1f);
                        wfrag[(8 + nt * 2 + s) * 64 + l2] = __builtin_bit_cast(uint4, w2f);
                    }
                }
#pragma unroll
                for (int nt = 0; nt < 2; nt++) {
#pragma unroll
                    for (int s = 0; s < 2; s++) {
                        half8 w3f;
#pragma unroll
                        for (int jj = 0; jj < 8; jj++) {
                            int ks = s * 32 + qq * 8 + jj;
                            w3f[jj] = (_Float16)W3[ks * 32 + nt * 16 + nn];
                        }
                        wfrag[(16 + nt * 2 + s) * 64 + l2] = __builtin_bit_cast(uint4, w3f);
                    }
                }
                bfrag[0 * 64 + l2] = make_float4(b1[nn], b1[16 + nn], b1[32 + nn], b1[48 + nn]);
                bfrag[1 * 64 + l2] = make_float4(b2[nn], b2[16 + nn], b2[32 + nn], b2[48 + nn]);
                bfrag[2 * 64 + l2] = make_float4(b3[nn], b3[16 + nn], W4[nn], W4[16 + nn]);
            }
        } else {
            int j = c * TPB + tid;
            int v = 0;
            if (j < J) {
                int ji   = job_indices[j];
                v        = num_exec_acts[ji];
                int node = ptr[ji];
                float f[40];
                f[0] = x[node * 5 + 0];
                f[1] = x[node * 5 + 1];
                f[2] = x[node * 5 + 2];
                float4 hd[4], hg[4];
#pragma unroll
                for (int c4 = 0; c4 < 4; c4++) hd[c4] = *(const float4*)(h_dag + (size_t)ji * 16 + 4 * c4);
#pragma unroll
                for (int c4 = 0; c4 < 4; c4++) hg[c4] = *(const float4*)(h_glob + (size_t)j * 16 + 4 * c4);
#pragma unroll
                for (int c4 = 0; c4 < 4; c4++) {
                    f[3 + 4 * c4 + 0]  = hd[c4].x; f[3 + 4 * c4 + 1]  = hd[c4].y;
                    f[3 + 4 * c4 + 2]  = hd[c4].z; f[3 + 4 * c4 + 3]  = hd[c4].w;
                    f[19 + 4 * c4 + 0] = hg[c4].x; f[19 + 4 * c4 + 1] = hg[c4].y;
                    f[19 + 4 * c4 + 2] = hg[c4].z; f[19 + 4 * c4 + 3] = hg[c4].w;
                }
#pragma unroll
                for (int cc = 35; cc < 40; cc++) f[cc] = 0.0f;
                unsigned int w[20];
#pragma unroll
                for (int k = 0; k < 20; k++)
                    w[k] = (unsigned)h2u((_Float16)f[2 * k]) | ((unsigned)h2u((_Float16)f[2 * k + 1]) << 16);
                uint4* dst = (uint4*)(feat + (size_t)j * 20);
#pragma unroll
                for (int qq = 0; qq < 5; qq++)
                    dst[qq] = make_uint4(w[4 * qq], w[4 * qq + 1], w[4 * qq + 2], w[4 * qq + 3]);
            }
            // inclusive scan of v (reuses boffs as scratch)
            boffs[tid] = v;
            __syncthreads();
            for (int d = 1; d < TPB; d <<= 1) {
                int add = (tid >= d) ? boffs[tid - d] : 0;
                __syncthreads();
                boffs[tid] += add;
                __syncthreads();
            }
            if (j < J) jsv[j] = ((boffs[tid] - v) << 6) | v;
            if (tid == TPB - 1) bsum[c] = boffs[TPB - 1];
        }
    }

    // ================= software grid barrier (device-scope, XCD-coherence-safe) =================
    __threadfence();                    // release: every thread's stores visible device-wide
    __syncthreads();
    if (tid == 0) {
        __hip_atomic_fetch_add(bar, 1, __ATOMIC_RELEASE, __HIP_MEMORY_SCOPE_AGENT);
        while (__hip_atomic_load(bar, __ATOMIC_ACQUIRE, __HIP_MEMORY_SCOPE_AGENT) < (int)gridDim.x)
            __builtin_amdgcn_s_sleep(8);
    }
    __syncthreads();
    __threadfence();                    // acquire: invalidate stale cached lines before reads

    // ================= PHASE B: MFMA MLP =================
    // block-local exclusive scan of bsum (nb <= 256)
    {
        int v = (tid < nb) ? bsum[tid] : 0;
        boffs[tid] = v;
        __syncthreads();
        for (int d = 1; d < TPB; d <<= 1) {
            int add = (tid >= d) ? boffs[tid - d] : 0;
            __syncthreads();
            boffs[tid] += add;
            __syncthreads();
        }
        int ex = boffs[tid] - v;
        __syncthreads();
        boffs[tid] = ex;
        __syncthreads();
    }

    // fragment loads: 23 coalesced 16B loads
    half8 bw1[4][2], bw2[4][2], bw3[2][2];
#pragma unroll
    for (int nt = 0; nt < 4; nt++)
#pragma unroll
        for (int s = 0; s < 2; s++) {
            bw1[nt][s] = __builtin_bit_cast(half8, wfrag[(nt * 2 + s) * 64 + lane]);
            bw2[nt][s] = __builtin_bit_cast(half8, wfrag[(8 + nt * 2 + s) * 64 + lane]);
        }
#pragma unroll
    for (int nt = 0; nt < 2; nt++)
#pragma unroll
        for (int s = 0; s < 2; s++)
            bw3[nt][s] = __builtin_bit_cast(half8, wfrag[(16 + nt * 2 + s) * 64 + lane]);

    float4 bf1 = bfrag[0 * 64 + lane];
    float4 bf2 = bfrag[1 * 64 + lane];
    float4 bf3 = bfrag[2 * 64 + lane];
    float bb1[4] = {bf1.x, bf1.y, bf1.z, bf1.w};
    float bb2[4] = {bf2.x, bf2.y, bf2.z, bf2.w};
    float bb3[2] = {bf3.x, bf3.y};
    const float w4a = bf3.z, w4b = bf3.w;
    const float b4v = b4[0];
    const int   swr = (n >> 1) & 7;
    const int   odd = n & 1;

    const int chunk = (numTiles + gridDim.x - 1) / gridDim.x;
    const int t0 = blockIdx.x * chunk;
    int t1 = t0 + chunk; if (t1 > numTiles) t1 = numTiles;
    if (t0 >= numTiles) return;
    const int R  = (t1 - t0) * 32;
    const int r0 = t0 * 128 + wv * R;
    int rend = r0 + R;
    if (rend > T) rend = T;

#define REFILL_SEARCH(RB)                                                        \
    {                                                                            \
        if (win_top <= (RB) + 31) {                                              \
            for (;;) {                                                           \
                int jj = j_lo + lane;                                            \
                sreg = (jj < J) ? (boffs[jj >> 8] + (jsv[jj] >> 6)) : 0x7fffffff;\
                unsigned long long m = __ballot(sreg <= (RB));                   \
                int adv = 63 - __builtin_clzll(m);                               \
                j_lo += adv;                                                     \
                if (adv == 0) break;                                             \
            }                                                                    \
            swin[wv][lane] = sreg;                                               \
            win_top = __shfl(sreg, 63);                                          \
        }                                                                        \
        if (lane < 32) {                                                         \
            int rt = (RB) + lane;                                                \
            const int* sw = swin[wv];                                            \
            int lj = 0;                                                          \
            _Pragma("unroll")                                                    \
            for (int stp = 32; stp; stp >>= 1) {                                 \
                int c2 = lj + stp;                                               \
                if (c2 < 64 && sw[c2] <= rt) lj = c2;                            \
            }                                                                    \
            srow[wv][lane] = (lj << 8) | (rt - sw[lj]);                          \
        }                                                                        \
    }

#define BUILD_A1(RB, A1)                                                         \
    {                                                                            \
        _Pragma("unroll")                                                        \
        for (int mt = 0; mt < 2; mt++) {                                         \
            int  rt    = (RB) + 16 * mt + n;                                     \
            bool valid = rt < T;                                                 \
            int  u     = srow[wv][16 * mt + n];                                  \
            int  jj2   = j_lo + (u >> 8);                                        \
            const uint4* fsrc = (const uint4*)(feat + (size_t)jj2 * 20);         \
            uint4 g0 = fsrc[q];                                                  \
            A1[mt][0] = __builtin_bit_cast(half8, g0);                           \
            uint4 g1 = make_uint4(0, 0, 0, 0);                                   \
            if (q == 0) {                                                        \
                g1 = fsrc[4];                                                    \
                float fe = valid ? (float)(u & 255) * 0.02f : 0.0f;              \
                g1.y = (g1.y & 0xffffu) | ((unsigned)h2u((_Float16)fe) << 16);   \
            }                                                                    \
            A1[mt][1] = __builtin_bit_cast(half8, g1);                           \
        }                                                                        \
    }

    if (r0 < rend) {
        int j_lo;
        {
            int lo = 0, hi = nb - 1;
            while (lo < hi) {
                int mid = (lo + hi + 1) >> 1;
                if (boffs[mid] <= r0) lo = mid; else hi = mid - 1;
            }
            j_lo = lo << 8;
        }
        int sreg    = 0;
        int win_top = 0x80000000;

        REFILL_SEARCH(r0);
        half8 a1[2][2];
        BUILD_A1(r0, a1);

        for (int rb = r0; rb < rend; rb += 32) {
            // ---- layer 1 MFMAs for both m-tiles (consume a1) ----
            f32x4 acc1[2][4];
#pragma unroll
            for (int mt = 0; mt < 2; mt++) {
#pragma unroll
                for (int nt = 0; nt < 4; nt++) { f32x4 c; c[0]=c[1]=c[2]=c[3]=bb1[nt]; acc1[mt][nt]=c; }
#pragma unroll
                for (int s = 0; s < 2; s++)
#pragma unroll
                    for (int nt = 0; nt < 4; nt++)
                        acc1[mt][nt] = __builtin_amdgcn_mfma_f32_16x16x32_f16(a1[mt][s], bw1[nt][s], acc1[mt][nt], 0, 0, 0);
            }

            // ---- prefetch next row-block (metadata + feature gathers) under the compute ----
            int rbn = rb + 32;
            if (rbn < rend) {
                REFILL_SEARCH(rbn);
                BUILD_A1(rbn, a1);
            }

            // ---- layer 1 repack -> slab ----
#pragma unroll
            for (int mt = 0; mt < 2; mt++) {
                unsigned* sl = (unsigned*)slab;
#pragma unroll
                for (int nt = 0; nt < 4; nt++) {
                    float v0 = fmaxf(acc1[mt][nt][0], 0.0f), v1 = fmaxf(acc1[mt][nt][1], 0.0f);
                    float v2 = fmaxf(acc1[mt][nt][2], 0.0f), v3 = fmaxf(acc1[mt][nt][3], 0.0f);
                    float t0_ = dppmov<DPP_SWAP>(v0), t1_ = dppmov<DPP_SWAP>(v1);
                    float t2_ = dppmov<DPP_SWAP>(v2), t3_ = dppmov<DPP_SWAP>(v3);
                    unsigned u0 = pkrtz(odd ? t2_ : v0, odd ? v2 : t0_);
                    unsigned u1 = pkrtz(odd ? t3_ : v1, odd ? v3 : t1_);
                    int rowA = 16 * mt + 4 * q + (odd ? 2 : 0);
                    int c    = 2 * nt + (n >> 3);
                    int a0   = (rowA * 8 + (c ^ ((rowA >> 1) & 7))) * 4 + ((n >> 1) & 3);
                    sl[a0] = u0; sl[a0 + 32] = u1;
                }
            }

            // ---- layer 2: slab -> slab (in-place; same-wave DS ops are in-order) ----
#pragma unroll
            for (int mt = 0; mt < 2; mt++) {
                const int M0 = 16 * mt;
                f32x4 acc[4];
#pragma unroll
                for (int nt = 0; nt < 4; nt++) { f32x4 c; c[0]=c[1]=c[2]=c[3]=bb2[nt]; acc[nt]=c; }
#pragma unroll
                for (int s = 0; s < 2; s++) {
                    half8 a = *(const half8*)(slab + ((M0 + n) * 8 + ((s * 4 + q) ^ swr)) * 16);
#pragma unroll
                    for (int nt = 0; nt < 4; nt++)
                        acc[nt] = __builtin_amdgcn_mfma_f32_16x16x32_f16(a, bw2[nt][s], acc[nt], 0, 0, 0);
                }
                unsigned* sl = (unsigned*)slab;
#pragma unroll
                for (int nt = 0; nt < 4; nt++) {
                    float v0 = fmaxf(acc[nt][0], 0.0f), v1 = fmaxf(acc[nt][1], 0.0f);
                    float v2 = fmaxf(acc[nt][2], 0.0f), v3 = fmaxf(acc[nt][3], 0.0f);
                    float t0_ = dppmov<DPP_SWAP>(v0), t1_ = dppmov<DPP_SWAP>(v1);
                    float t2_ = dppmov<DPP_SWAP>(v2), t3_ = dppmov<DPP_SWAP>(v3);
                    unsigned u0 = pkrtz(odd ? t2_ : v0, odd ? v2 : t0_);
                    unsigned u1 = pkrtz(odd ? t3_ : v1, odd ? v3 : t1_);
                    int rowA = M0 + 4 * q + (odd ? 2 : 0);
                    int c    = 2 * nt + (n >> 3);
                    int a0   = (rowA * 8 + (c ^ ((rowA >> 1) & 7))) * 4 + ((n >> 1) & 3);
                    sl[a0] = u0; sl[a0 + 32] = u1;
                }
            }

            // ---- layer 3 + 4: slab -> scores ----
#pragma unroll
            for (int mt = 0; mt < 2; mt++) {
                const int M0 = 16 * mt;
                f32x4 acc[2];
#pragma unroll
                for (int nt = 0; nt < 2; nt++) { f32x4 c; c[0]=c[1]=c[2]=c[3]=bb3[nt]; acc[nt]=c; }
#pragma unroll
                for (int s = 0; s < 2; s++) {
                    half8 a = *(const half8*)(slab + ((M0 + n) * 8 + ((s * 4 + q) ^ swr)) * 16);
#pragma unroll
                    for (int nt = 0; nt < 2; nt++)
                        acc[nt] = __builtin_amdgcn_mfma_f32_16x16x32_f16(a, bw3[nt][s], acc[nt], 0, 0, 0);
                }
                f32x4 red;
#pragma unroll
                for (int r = 0; r < 4; r++)
                    red[r] = fmaxf(acc[0][r], 0.0f) * w4a + fmaxf(acc[1][r], 0.0f) * w4b;
#pragma unroll
                for (int r = 0; r < 4; r++) {
                    red[r] += dppmov<0x121>(red[r]);   // row_ror:1
                    red[r] += dppmov<0x122>(red[r]);   // row_ror:2
                    red[r] += dppmov<0x124>(red[r]);   // row_ror:4
                    red[r] += dppmov<0x128>(red[r]);   // row_ror:8
                }
                int t = rb + M0 + q * 4 + n;
                float val = (n == 0) ? red[0] : (n == 1) ? red[1] : (n == 2) ? red[2] : red[3];
                if (n < 4 && t < T) out[t] = val + b4v;
            }
        }
    }
#undef REFILL_SEARCH
#undef BUILD_A1
}

extern "C" void kernel_launch(void* const* d_in, const int* in_sizes, int n_in,
                              void* d_out, int out_size, void* d_ws, size_t ws_size,
                              hipStream_t stream)
{
    const float* x             = (const float*)d_in[0];
    const float* h_dag         = (const float*)d_in[1];
    const float* h_glob        = (const float*)d_in[2];
    const int*   ptr           = (const int*)d_in[3];
    const int*   job_indices   = (const int*)d_in[4];
    const int*   num_exec_acts = (const int*)d_in[5];
    const float* W1 = (const float*)d_in[7];
    const float* b1 = (const float*)d_in[8];
    const float* W2 = (const float*)d_in[9];
    const float* b2 = (const float*)d_in[10];
    const float* W3 = (const float*)d_in[11];
    const float* b3 = (const float*)d_in[12];
    const float* W4 = (const float*)d_in[13];
    const float* b4 = (const float*)d_in[14];
    float* out = (float*)d_out;

    int J  = in_sizes[4];
    int T  = in_sizes[6];
    int nb = (J + TPB - 1) / TPB;

    // workspace layout
    char* wsp = (char*)d_ws;
    int* bar = (int*)wsp;
    wsp += 256;
    int* bsum = (int*)wsp;
    wsp += (((size_t)nb * 4) + 255) / 256 * 256;
    int* jsv = (int*)wsp;
    wsp += (((size_t)J * 4) + 255) / 256 * 256;
    uint4* wfrag = (uint4*)wsp;            // 20*64*16 B
    wsp += 20 * 64 * 16;
    float4* bfrag = (float4*)wsp;          // 3*64*16 B
    wsp += 3 * 64 * 16;
    unsigned int* feat = (unsigned int*)wsp;   // J*20 words

    int numTiles = (T + 127) / 128;

    // grid sized for guaranteed co-residency (software grid barrier requirement)
    static int g_grid = 0;
    if (g_grid == 0) {
        int dev = 0, cus = 0, bpc = 0;
        hipGetDevice(&dev);
        hipDeviceGetAttribute(&cus, hipDeviceAttributeMultiprocessorCount, dev);
        hipOccupancyMaxActiveBlocksPerMultiprocessor(&bpc, k_fused, TPB, 0);
        if (cus <= 0) cus = 256;
        if (bpc <= 0) bpc = 1;
        long long g = (long long)cus * bpc;
        if (g > 2048) g = 2048;
        g_grid = (int)g;
    }
    int grid = g_grid;

    hipMemsetAsync(bar, 0, 8, stream);
    k_fused<<<grid, TPB, 0, stream>>>(x, h_dag, h_glob, ptr, job_indices, num_exec_acts,
                                      W1, b1, W2, b2, W3, b3, W4, b4,
                                      feat, bsum, jsv, wfrag, bfrag, out, bar,
                                      J, nb, T, numTiles);
}

// Round 5
// 180.174 us; speedup vs baseline: 1.5954x; 1.5954x over previous
//
#include <hip/hip_runtime.h>

#define TPB 256

using half8  = __attribute__((ext_vector_type(8))) _Float16;
using fp16x2 = __attribute__((ext_vector_type(2))) __fp16;
using f32x4  = __attribute__((ext_vector_type(4))) float;

static __device__ __forceinline__ unsigned short h2u(_Float16 h) {
    union { _Float16 h; unsigned short u; } v; v.h = h; return v.u;
}
static __device__ __forceinline__ unsigned pkrtz(float a, float b) {
    fp16x2 h = __builtin_amdgcn_cvt_pkrtz(a, b);
    return __builtin_bit_cast(unsigned, h);
}
template <int CTRL>
static __device__ __forceinline__ float dppmov(float x) {
    return __int_as_float(__builtin_amdgcn_mov_dpp(__float_as_int(x), CTRL, 0xF, 0xF, true));
}
#define DPP_SWAP 0xB1   // quad_perm [1,0,3,2]

// ---------- kernel 1: pack fp16 features + local scan; extra block builds weight fragments ----------
__global__ __launch_bounds__(TPB) void k_prep(const float* __restrict__ x,
                                              const float* __restrict__ h_dag,
                                              const float* __restrict__ h_glob,
                                              const int* __restrict__ ptr,
                                              const int* __restrict__ job_indices,
                                              const int* __restrict__ num_exec_acts,
                                              int J, int nb,
                                              unsigned int* __restrict__ feat,
                                              int* __restrict__ bsum, int* __restrict__ jsv,
                                              const float* __restrict__ W1,
                                              const float* __restrict__ b1,
                                              const float* __restrict__ W2,
                                              const float* __restrict__ b2,
                                              const float* __restrict__ W3,
                                              const float* __restrict__ b3,
                                              const float* __restrict__ W4,
                                              uint4* __restrict__ wfrag,
                                              float4* __restrict__ bfrag)
{
    if (blockIdx.x == (unsigned)nb) {
        // ---- weight/bias fragment build (independent of scan; 64 lanes) ----
        if (threadIdx.x < 64) {
            int lane = threadIdx.x;
            int n = lane & 15, q = lane >> 4;
#pragma unroll
            for (int nt = 0; nt < 4; nt++) {
#pragma unroll
                for (int s = 0; s < 2; s++) {
                    half8 w1f, w2f;
#pragma unroll
                    for (int jj = 0; jj < 8; jj++) {
                        int ks = s * 32 + q * 8 + jj;
                        w1f[jj] = (ks < 36) ? (_Float16)W1[ks * 64 + nt * 16 + n] : (_Float16)0.0f;
                        w2f[jj] = (_Float16)W2[ks * 64 + nt * 16 + n];
                    }
                    wfrag[(nt * 2 + s) * 64 + lane]     = __builtin_bit_cast(uint4, w1f);
                    wfrag[(8 + nt * 2 + s) * 64 + lane] = __builtin_bit_cast(uint4, w2f);
                }
            }
#pragma unroll
            for (int nt = 0; nt < 2; nt++) {
#pragma unroll
                for (int s = 0; s < 2; s++) {
                    half8 w3f;
#pragma unroll
                    for (int jj = 0; jj < 8; jj++) {
                        int ks = s * 32 + q * 8 + jj;
                        w3f[jj] = (_Float16)W3[ks * 32 + nt * 16 + n];
                    }
                    wfrag[(16 + nt * 2 + s) * 64 + lane] = __builtin_bit_cast(uint4, w3f);
                }
            }
            bfrag[0 * 64 + lane] = make_float4(b1[n], b1[16 + n], b1[32 + n], b1[48 + n]);
            bfrag[1 * 64 + lane] = make_float4(b2[n], b2[16 + n], b2[32 + n], b2[48 + n]);
            bfrag[2 * 64 + lane] = make_float4(b3[n], b3[16 + n], W4[n], W4[16 + n]);
        }
        return;
    }

    __shared__ int sc[TPB];
    int j = blockIdx.x * TPB + threadIdx.x;
    int v = 0;
    if (j < J) {
        int ji   = job_indices[j];
        v        = num_exec_acts[ji];
        int node = ptr[ji];
        float f[40];
        f[0] = x[node * 5 + 0];
        f[1] = x[node * 5 + 1];
        f[2] = x[node * 5 + 2];
        // vectorized gathers: ji*16 floats = 64B aligned
        float4 hd[4], hg[4];
#pragma unroll
        for (int c4 = 0; c4 < 4; c4++) hd[c4] = *(const float4*)(h_dag + (size_t)ji * 16 + 4 * c4);
#pragma unroll
        for (int c4 = 0; c4 < 4; c4++) hg[c4] = *(const float4*)(h_glob + (size_t)j * 16 + 4 * c4);
#pragma unroll
        for (int c4 = 0; c4 < 4; c4++) {
            f[3 + 4 * c4 + 0]  = hd[c4].x; f[3 + 4 * c4 + 1]  = hd[c4].y;
            f[3 + 4 * c4 + 2]  = hd[c4].z; f[3 + 4 * c4 + 3]  = hd[c4].w;
            f[19 + 4 * c4 + 0] = hg[c4].x; f[19 + 4 * c4 + 1] = hg[c4].y;
            f[19 + 4 * c4 + 2] = hg[c4].z; f[19 + 4 * c4 + 3] = hg[c4].w;
        }
#pragma unroll
        for (int c = 35; c < 40; c++) f[c] = 0.0f;
        unsigned int w[20];
#pragma unroll
        for (int k = 0; k < 20; k++)
            w[k] = (unsigned)h2u((_Float16)f[2 * k]) | ((unsigned)h2u((_Float16)f[2 * k + 1]) << 16);
        uint4* dst = (uint4*)(feat + (size_t)j * 20);
#pragma unroll
        for (int qq = 0; qq < 5; qq++)
            dst[qq] = make_uint4(w[4 * qq], w[4 * qq + 1], w[4 * qq + 2], w[4 * qq + 3]);
    }
    // inclusive scan of v
    sc[threadIdx.x] = v;
    __syncthreads();
    for (int d = 1; d < TPB; d <<= 1) {
        int add = (threadIdx.x >= d) ? sc[threadIdx.x - d] : 0;
        __syncthreads();
        sc[threadIdx.x] += add;
        __syncthreads();
    }
    if (j < J) jsv[j] = ((sc[threadIdx.x] - v) << 6) | v;
    if (threadIdx.x == TPB - 1) bsum[blockIdx.x] = sc[TPB - 1];
}

// ---------- kernel 2: fused MFMA MLP; 64-row macro-steps, full-wave search, 4-mt gather ILP ----------
__global__ __launch_bounds__(TPB) void k_mlp_mfma(const unsigned int* __restrict__ feat,
                                                  const int* __restrict__ jsv,
                                                  const int* __restrict__ bsum,
                                                  const uint4* __restrict__ wfrag,
                                                  const float4* __restrict__ bfrag,
                                                  const float* __restrict__ b4,
                                                  float* __restrict__ out,
                                                  int T, int J, int nb, int numTiles, int chunk)
{
    __shared__ __align__(16) char smem[4 * 4096];   // one 4 KB slab per wave (reused across layers)
    __shared__ int boffs[TPB];                       // exclusive scan of bsum
    __shared__ int swin[4][64];                      // per-wave job-start window
    __shared__ int srow[4][64];                      // per-wave per-row (job<<8|exec) for 64 rows
    const int tid  = threadIdx.x;
    const int lane = tid & 63;
    const int wv   = tid >> 6;
    const int n    = lane & 15;
    const int q    = lane >> 4;
    char* slab = smem + wv * 4096;

    // ---- block-local exclusive scan of bsum (nb <= 256) ----
    {
        int v = (tid < nb) ? bsum[tid] : 0;
        boffs[tid] = v;
        __syncthreads();
        for (int d = 1; d < TPB; d <<= 1) {
            int add = (tid >= d) ? boffs[tid - d] : 0;
            __syncthreads();
            boffs[tid] += add;
            __syncthreads();
        }
        int ex = boffs[tid] - v;
        __syncthreads();
        boffs[tid] = ex;
        __syncthreads();
    }

    // ---- fragment loads: 23 coalesced 16B loads ----
    half8 bw1[4][2], bw2[4][2], bw3[2][2];
#pragma unroll
    for (int nt = 0; nt < 4; nt++)
#pragma unroll
        for (int s = 0; s < 2; s++) {
            bw1[nt][s] = __builtin_bit_cast(half8, wfrag[(nt * 2 + s) * 64 + lane]);
            bw2[nt][s] = __builtin_bit_cast(half8, wfrag[(8 + nt * 2 + s) * 64 + lane]);
        }
#pragma unroll
    for (int nt = 0; nt < 2; nt++)
#pragma unroll
        for (int s = 0; s < 2; s++)
            bw3[nt][s] = __builtin_bit_cast(half8, wfrag[(16 + nt * 2 + s) * 64 + lane]);

    float4 bf1 = bfrag[0 * 64 + lane];
    float4 bf2 = bfrag[1 * 64 + lane];
    float4 bf3 = bfrag[2 * 64 + lane];
    float bb1[4] = {bf1.x, bf1.y, bf1.z, bf1.w};
    float bb2[4] = {bf2.x, bf2.y, bf2.z, bf2.w};
    float bb3[2] = {bf3.x, bf3.y};
    const float w4a = bf3.z, w4b = bf3.w;
    const float b4v = b4[0];
    const int   swr = (n >> 1) & 7;
    const int   odd = n & 1;

    // ---- per-block contiguous tile range; wave wv owns the wv-th quarter (contiguous rows) ----
    const int t0 = blockIdx.x * chunk;
    const int t1 = (t0 + chunk < numTiles) ? (t0 + chunk) : numTiles;
    const int R  = (t1 - t0) * 32;                 // rows per wave (multiple of 32)
    const int r0 = t0 * 128 + wv * R;              // first row of this wave
    int rend = r0 + R;
    if (rend > T) rend = T;

    if (r0 < rend) {
        // initial cursor: prep-block whose exclusive offset <= r0
        int j_lo;
        {
            int lo = 0, hi = nb - 1;
            while (lo < hi) {
                int mid = (lo + hi + 1) >> 1;
                if (boffs[mid] <= r0) lo = mid; else hi = mid - 1;
            }
            j_lo = lo << 8;   // jstart(j_lo) = boffs[lo] <= r0
        }
        int sreg    = 0;
        int win_top = 0x80000000;   // forces first refill

        // 32-row compute body (identical to round-3 body); ab selects a1 slice (0 or 2)
        half8 a1[4][2];
        auto body32 = [&](int rbb, int ab) {
            // ---- layer 1 -> slab ----
#pragma unroll
            for (int mt = 0; mt < 2; mt++) {
                f32x4 acc[4];
#pragma unroll
                for (int nt = 0; nt < 4; nt++) { f32x4 c; c[0]=c[1]=c[2]=c[3]=bb1[nt]; acc[nt]=c; }
#pragma unroll
                for (int s = 0; s < 2; s++) {
#pragma unroll
                    for (int nt = 0; nt < 4; nt++)
                        acc[nt] = __builtin_amdgcn_mfma_f32_16x16x32_f16(a1[ab + mt][s], bw1[nt][s], acc[nt], 0, 0, 0);
                }
                unsigned* sl = (unsigned*)slab;
#pragma unroll
                for (int nt = 0; nt < 4; nt++) {
                    float v0 = fmaxf(acc[nt][0], 0.0f), v1 = fmaxf(acc[nt][1], 0.0f);
                    float v2 = fmaxf(acc[nt][2], 0.0f), v3 = fmaxf(acc[nt][3], 0.0f);
                    float t0_ = dppmov<DPP_SWAP>(v0), t1_ = dppmov<DPP_SWAP>(v1);
                    float t2_ = dppmov<DPP_SWAP>(v2), t3_ = dppmov<DPP_SWAP>(v3);
                    unsigned u0 = pkrtz(odd ? t2_ : v0, odd ? v2 : t0_);
                    unsigned u1 = pkrtz(odd ? t3_ : v1, odd ? v3 : t1_);
                    int rowA = 16 * mt + 4 * q + (odd ? 2 : 0);
                    int c    = 2 * nt + (n >> 3);
                    int a0   = (rowA * 8 + (c ^ ((rowA >> 1) & 7))) * 4 + ((n >> 1) & 3);
                    sl[a0] = u0; sl[a0 + 32] = u1;
                }
            }

            // ---- layer 2: slab -> slab (in-place; same-wave DS ops are in-order) ----
#pragma unroll
            for (int mt = 0; mt < 2; mt++) {
                const int M0 = 16 * mt;
                f32x4 acc[4];
#pragma unroll
                for (int nt = 0; nt < 4; nt++) { f32x4 c; c[0]=c[1]=c[2]=c[3]=bb2[nt]; acc[nt]=c; }
#pragma unroll
                for (int s = 0; s < 2; s++) {
                    half8 a = *(const half8*)(slab + ((M0 + n) * 8 + ((s * 4 + q) ^ swr)) * 16);
#pragma unroll
                    for (int nt = 0; nt < 4; nt++)
                        acc[nt] = __builtin_amdgcn_mfma_f32_16x16x32_f16(a, bw2[nt][s], acc[nt], 0, 0, 0);
                }
                unsigned* sl = (unsigned*)slab;
#pragma unroll
                for (int nt = 0; nt < 4; nt++) {
                    float v0 = fmaxf(acc[nt][0], 0.0f), v1 = fmaxf(acc[nt][1], 0.0f);
                    float v2 = fmaxf(acc[nt][2], 0.0f), v3 = fmaxf(acc[nt][3], 0.0f);
                    float t0_ = dppmov<DPP_SWAP>(v0), t1_ = dppmov<DPP_SWAP>(v1);
                    float t2_ = dppmov<DPP_SWAP>(v2), t3_ = dppmov<DPP_SWAP>(v3);
                    unsigned u0 = pkrtz(odd ? t2_ : v0, odd ? v2 : t0_);
                    unsigned u1 = pkrtz(odd ? t3_ : v1, odd ? v3 : t1_);
                    int rowA = M0 + 4 * q + (odd ? 2 : 0);
                    int c    = 2 * nt + (n >> 3);
                    int a0   = (rowA * 8 + (c ^ ((rowA >> 1) & 7))) * 4 + ((n >> 1) & 3);
                    sl[a0] = u0; sl[a0 + 32] = u1;
                }
            }

            // ---- layer 3 + 4: slab -> scores ----
#pragma unroll
            for (int mt = 0; mt < 2; mt++) {
                const int M0 = 16 * mt;
                f32x4 acc[2];
#pragma unroll
                for (int nt = 0; nt < 2; nt++) { f32x4 c; c[0]=c[1]=c[2]=c[3]=bb3[nt]; acc[nt]=c; }
#pragma unroll
                for (int s = 0; s < 2; s++) {
                    half8 a = *(const half8*)(slab + ((M0 + n) * 8 + ((s * 4 + q) ^ swr)) * 16);
#pragma unroll
                    for (int nt = 0; nt < 2; nt++)
                        acc[nt] = __builtin_amdgcn_mfma_f32_16x16x32_f16(a, bw3[nt][s], acc[nt], 0, 0, 0);
                }
                f32x4 red;
#pragma unroll
                for (int r = 0; r < 4; r++)
                    red[r] = fmaxf(acc[0][r], 0.0f) * w4a + fmaxf(acc[1][r], 0.0f) * w4b;
#pragma unroll
                for (int r = 0; r < 4; r++) {
                    red[r] += dppmov<0x121>(red[r]);   // row_ror:1
                    red[r] += dppmov<0x122>(red[r]);   // row_ror:2
                    red[r] += dppmov<0x124>(red[r]);   // row_ror:4
                    red[r] += dppmov<0x128>(red[r]);   // row_ror:8
                }
                int t = rbb + M0 + q * 4 + n;
                float val = (n == 0) ? red[0] : (n == 1) ? red[1] : (n == 2) ? red[2] : red[3];
                if (n < 4 && t < T) out[t] = val + b4v;
            }
        };

        for (int rb = r0; rb < rend; rb += 64) {
            // ---- refill job-start window when it may not cover [rb, rb+64) ----
            // post-advance invariant: jstart(j_lo+1) > rb  =>  jstart(j_lo+64) >= rb+64,
            // so every row <= rb+63 resolves inside the 64-job window.
            if (win_top <= rb + 63) {
                for (;;) {
                    int jj = j_lo + lane;
                    sreg = (jj < J) ? (boffs[jj >> 8] + (jsv[jj] >> 6)) : 0x7fffffff;
                    unsigned long long m = __ballot(sreg <= rb);
                    int adv = 63 - __builtin_clzll(m);   // bit0 always set (invariant)
                    j_lo += adv;
                    if (adv == 0) break;
                }
                swin[wv][lane] = sreg;
                win_top = __shfl(sreg, 63);
            }

            // ---- full-wave per-row search: lane resolves row rb+lane ----
            {
                int rt = rb + lane;
                const int* sw = swin[wv];
                int lj = 0;
#pragma unroll
                for (int stp = 32; stp; stp >>= 1) {
                    int c2 = lj + stp;
                    if (c2 < 64 && sw[c2] <= rt) lj = c2;
                }
                srow[wv][lane] = (lj << 8) | (rt - sw[lj]);   // exec fits 8 bits
            }
            // same-wave LDS: DS pipe is in-order, no barrier needed

            // ---- A1 fragments for ALL 4 m-tiles issued together (mt2/3 latency hides under body 1) ----
#pragma unroll
            for (int mt = 0; mt < 4; mt++) {
                int  rt    = rb + 16 * mt + n;
                bool valid = rt < T;
                int  u     = srow[wv][16 * mt + n];
                int  jj2   = j_lo + (u >> 8);
                const uint4* fsrc = (const uint4*)(feat + (size_t)jj2 * 20);
                uint4 g0 = fsrc[q];
                a1[mt][0] = __builtin_bit_cast(half8, g0);
                uint4 g1 = make_uint4(0, 0, 0, 0);
                if (q == 0) {
                    g1 = fsrc[4];
                    float fe = valid ? (float)(u & 255) * 0.02f : 0.0f;  // exec_act_idx == rt - jstart
                    g1.y = (g1.y & 0xffffu) | ((unsigned)h2u((_Float16)fe) << 16);
                }
                a1[mt][1] = __builtin_bit_cast(half8, g1);
            }

            body32(rb, 0);
            if (rb + 32 < rend) body32(rb + 32, 2);
        }
    }
}

extern "C" void kernel_launch(void* const* d_in, const int* in_sizes, int n_in,
                              void* d_out, int out_size, void* d_ws, size_t ws_size,
                              hipStream_t stream)
{
    const float* x             = (const float*)d_in[0];
    const float* h_dag         = (const float*)d_in[1];
    const float* h_glob        = (const float*)d_in[2];
    const int*   ptr           = (const int*)d_in[3];
    const int*   job_indices   = (const int*)d_in[4];
    const int*   num_exec_acts = (const int*)d_in[5];
    const float* W1 = (const float*)d_in[7];
    const float* b1 = (const float*)d_in[8];
    const float* W2 = (const float*)d_in[9];
    const float* b2 = (const float*)d_in[10];
    const float* W3 = (const float*)d_in[11];
    const float* b3 = (const float*)d_in[12];
    const float* W4 = (const float*)d_in[13];
    const float* b4 = (const float*)d_in[14];
    float* out = (float*)d_out;

    int J  = in_sizes[4];
    int T  = in_sizes[6];
    int nb = (J + TPB - 1) / TPB;

    // workspace layout
    char* wsp = (char*)d_ws;
    int* bsum = (int*)wsp;
    wsp += (((size_t)nb * 4) + 255) / 256 * 256;
    int* jsv = (int*)wsp;
    wsp += (((size_t)J * 4) + 255) / 256 * 256;
    uint4* wfrag = (uint4*)wsp;            // 20*64*16 B
    wsp += 20 * 64 * 16;
    float4* bfrag = (float4*)wsp;          // 3*64*16 B
    wsp += 3 * 64 * 16;
    unsigned int* feat = (unsigned int*)wsp;   // J*20 words

    k_prep<<<nb + 1, TPB, 0, stream>>>(x, h_dag, h_glob, ptr, job_indices, num_exec_acts,
                                       J, nb, feat, bsum, jsv,
                                       W1, b1, W2, b2, W3, b3, W4, wfrag, bfrag);

    int numTiles = (T + 127) / 128;
    int grid = numTiles < 1280 ? numTiles : 1280;
    int chunk = (numTiles + grid - 1) / grid;
    grid = (numTiles + chunk - 1) / chunk;
    k_mlp_mfma<<<grid, TPB, 0, stream>>>(feat, jsv, bsum, wfrag, bfrag, b4,
                                         out, T, J, nb, numTiles, chunk);
}

// Round 6
// 175.324 us; speedup vs baseline: 1.6395x; 1.0277x over previous
//
#include <hip/hip_runtime.h>

#define TPB 256

using half8  = __attribute__((ext_vector_type(8))) _Float16;
using fp16x2 = __attribute__((ext_vector_type(2))) __fp16;
using f32x4  = __attribute__((ext_vector_type(4))) float;

static __device__ __forceinline__ unsigned short h2u(_Float16 h) {
    union { _Float16 h; unsigned short u; } v; v.h = h; return v.u;
}
static __device__ __forceinline__ unsigned pkrtz(float a, float b) {
    fp16x2 h = __builtin_amdgcn_cvt_pkrtz(a, b);
    return __builtin_bit_cast(unsigned, h);
}
template <int CTRL>
static __device__ __forceinline__ float dppmov(float x) {
    return __int_as_float(__builtin_amdgcn_mov_dpp(__float_as_int(x), CTRL, 0xF, 0xF, true));
}
#define DPP_SWAP 0xB1   // quad_perm [1,0,3,2]

// ---------- kernel 1: pack fp16 features + local scan; extra block builds weight fragments ----------
__global__ __launch_bounds__(TPB) void k_prep(const float* __restrict__ x,
                                              const float* __restrict__ h_dag,
                                              const float* __restrict__ h_glob,
                                              const int* __restrict__ ptr,
                                              const int* __restrict__ job_indices,
                                              const int* __restrict__ num_exec_acts,
                                              int J, int nb,
                                              unsigned int* __restrict__ feat,
                                              int* __restrict__ bsum, int* __restrict__ jsv,
                                              const float* __restrict__ W1,
                                              const float* __restrict__ b1,
                                              const float* __restrict__ W2,
                                              const float* __restrict__ b2,
                                              const float* __restrict__ W3,
                                              const float* __restrict__ b3,
                                              const float* __restrict__ W4,
                                              uint4* __restrict__ wfrag,
                                              float4* __restrict__ bfrag)
{
    if (blockIdx.x == (unsigned)nb) {
        // ---- weight/bias fragment build (independent of scan; 64 lanes) ----
        if (threadIdx.x < 64) {
            int lane = threadIdx.x;
            int n = lane & 15, q = lane >> 4;
#pragma unroll
            for (int nt = 0; nt < 4; nt++) {
#pragma unroll
                for (int s = 0; s < 2; s++) {
                    half8 w1f, w2f;
#pragma unroll
                    for (int jj = 0; jj < 8; jj++) {
                        int ks = s * 32 + q * 8 + jj;
                        w1f[jj] = (ks < 36) ? (_Float16)W1[ks * 64 + nt * 16 + n] : (_Float16)0.0f;
                        w2f[jj] = (_Float16)W2[ks * 64 + nt * 16 + n];
                    }
                    wfrag[(nt * 2 + s) * 64 + lane]     = __builtin_bit_cast(uint4, w1f);
                    wfrag[(8 + nt * 2 + s) * 64 + lane] = __builtin_bit_cast(uint4, w2f);
                }
            }
#pragma unroll
            for (int nt = 0; nt < 2; nt++) {
#pragma unroll
                for (int s = 0; s < 2; s++) {
                    half8 w3f;
#pragma unroll
                    for (int jj = 0; jj < 8; jj++) {
                        int ks = s * 32 + q * 8 + jj;
                        w3f[jj] = (_Float16)W3[ks * 32 + nt * 16 + n];
                    }
                    wfrag[(16 + nt * 2 + s) * 64 + lane] = __builtin_bit_cast(uint4, w3f);
                }
            }
            bfrag[0 * 64 + lane] = make_float4(b1[n], b1[16 + n], b1[32 + n], b1[48 + n]);
            bfrag[1 * 64 + lane] = make_float4(b2[n], b2[16 + n], b2[32 + n], b2[48 + n]);
            bfrag[2 * 64 + lane] = make_float4(b3[n], b3[16 + n], W4[n], W4[16 + n]);
        }
        return;
    }

    __shared__ int sc[TPB];
    int j = blockIdx.x * TPB + threadIdx.x;
    int v = 0;
    if (j < J) {
        int ji   = job_indices[j];
        v        = num_exec_acts[ji];
        int node = ptr[ji];
        float f[40];
        f[0] = x[node * 5 + 0];
        f[1] = x[node * 5 + 1];
        f[2] = x[node * 5 + 2];
        // vectorized gathers: ji*16 floats = 64B aligned
        float4 hd[4], hg[4];
#pragma unroll
        for (int c4 = 0; c4 < 4; c4++) hd[c4] = *(const float4*)(h_dag + (size_t)ji * 16 + 4 * c4);
#pragma unroll
        for (int c4 = 0; c4 < 4; c4++) hg[c4] = *(const float4*)(h_glob + (size_t)j * 16 + 4 * c4);
#pragma unroll
        for (int c4 = 0; c4 < 4; c4++) {
            f[3 + 4 * c4 + 0]  = hd[c4].x; f[3 + 4 * c4 + 1]  = hd[c4].y;
            f[3 + 4 * c4 + 2]  = hd[c4].z; f[3 + 4 * c4 + 3]  = hd[c4].w;
            f[19 + 4 * c4 + 0] = hg[c4].x; f[19 + 4 * c4 + 1] = hg[c4].y;
            f[19 + 4 * c4 + 2] = hg[c4].z; f[19 + 4 * c4 + 3] = hg[c4].w;
        }
#pragma unroll
        for (int c = 35; c < 40; c++) f[c] = 0.0f;
        unsigned int w[20];
#pragma unroll
        for (int k = 0; k < 20; k++)
            w[k] = (unsigned)h2u((_Float16)f[2 * k]) | ((unsigned)h2u((_Float16)f[2 * k + 1]) << 16);
        uint4* dst = (uint4*)(feat + (size_t)j * 20);
#pragma unroll
        for (int qq = 0; qq < 5; qq++)
            dst[qq] = make_uint4(w[4 * qq], w[4 * qq + 1], w[4 * qq + 2], w[4 * qq + 3]);
    }
    // inclusive scan of v
    sc[threadIdx.x] = v;
    __syncthreads();
    for (int d = 1; d < TPB; d <<= 1) {
        int add = (threadIdx.x >= d) ? sc[threadIdx.x - d] : 0;
        __syncthreads();
        sc[threadIdx.x] += add;
        __syncthreads();
    }
    if (j < J) jsv[j] = ((sc[threadIdx.x] - v) << 6) | v;
    if (threadIdx.x == TPB - 1) bsum[blockIdx.x] = sc[TPB - 1];
}

// ---------- kernel 2: fused MFMA MLP; 64-row macro-steps, 2-slab software pipeline ----------
__global__ __launch_bounds__(TPB) void k_mlp_mfma(const unsigned int* __restrict__ feat,
                                                  const int* __restrict__ jsv,
                                                  const int* __restrict__ bsum,
                                                  const uint4* __restrict__ wfrag,
                                                  const float4* __restrict__ bfrag,
                                                  const float* __restrict__ b4,
                                                  float* __restrict__ out,
                                                  int T, int J, int nb, int numTiles, int chunk)
{
    __shared__ __align__(16) char smem[4 * 8192];   // TWO 4 KB slabs per wave (A/B pipeline)
    __shared__ int boffs[TPB];                       // exclusive scan of bsum
    __shared__ int swin[4][64];                      // per-wave job-start window
    __shared__ int srow[4][64];                      // per-wave per-row (job<<8|exec) for 64 rows
    const int tid  = threadIdx.x;
    const int lane = tid & 63;
    const int wv   = tid >> 6;
    const int n    = lane & 15;
    const int q    = lane >> 4;
    char* slabA = smem + wv * 8192;
    char* slabB = slabA + 4096;

    // ---- block-local exclusive scan of bsum (nb <= 256) ----
    {
        int v = (tid < nb) ? bsum[tid] : 0;
        boffs[tid] = v;
        __syncthreads();
        for (int d = 1; d < TPB; d <<= 1) {
            int add = (tid >= d) ? boffs[tid - d] : 0;
            __syncthreads();
            boffs[tid] += add;
            __syncthreads();
        }
        int ex = boffs[tid] - v;
        __syncthreads();
        boffs[tid] = ex;
        __syncthreads();
    }

    // ---- fragment loads: 23 coalesced 16B loads ----
    half8 bw1[4][2], bw2[4][2], bw3[2][2];
#pragma unroll
    for (int nt = 0; nt < 4; nt++)
#pragma unroll
        for (int s = 0; s < 2; s++) {
            bw1[nt][s] = __builtin_bit_cast(half8, wfrag[(nt * 2 + s) * 64 + lane]);
            bw2[nt][s] = __builtin_bit_cast(half8, wfrag[(8 + nt * 2 + s) * 64 + lane]);
        }
#pragma unroll
    for (int nt = 0; nt < 2; nt++)
#pragma unroll
        for (int s = 0; s < 2; s++)
            bw3[nt][s] = __builtin_bit_cast(half8, wfrag[(16 + nt * 2 + s) * 64 + lane]);

    float4 bf1 = bfrag[0 * 64 + lane];
    float4 bf2 = bfrag[1 * 64 + lane];
    float4 bf3 = bfrag[2 * 64 + lane];
    float bb1[4] = {bf1.x, bf1.y, bf1.z, bf1.w};
    float bb2[4] = {bf2.x, bf2.y, bf2.z, bf2.w};
    float bb3[2] = {bf3.x, bf3.y};
    const float w4a = bf3.z, w4b = bf3.w;
    const float b4v = b4[0];
    const int   swr = (n >> 1) & 7;
    const int   odd = n & 1;

    // ---- per-block contiguous tile range; wave wv owns the wv-th quarter (contiguous rows) ----
    const int t0 = blockIdx.x * chunk;
    const int t1 = (t0 + chunk < numTiles) ? (t0 + chunk) : numTiles;
    const int R  = (t1 - t0) * 32;                 // rows per wave (multiple of 32)
    const int r0 = t0 * 128 + wv * R;              // first row of this wave
    int rend = r0 + R;
    if (rend > T) rend = T;

    if (r0 < rend) {
        // initial cursor: prep-block whose exclusive offset <= r0
        int j_lo;
        {
            int lo = 0, hi = nb - 1;
            while (lo < hi) {
                int mid = (lo + hi + 1) >> 1;
                if (boffs[mid] <= r0) lo = mid; else hi = mid - 1;
            }
            j_lo = lo << 8;   // jstart(j_lo) = boffs[lo] <= r0
        }
        int sreg    = 0;
        int win_top = 0x80000000;   // forces first refill

        half8 a1[4][2];

        // ---- stage 1: layer-1 MFMAs + repack -> slab (rows ab*16 .. ab*16+31) ----
        auto stage_L1 = [&](char* slab, int ab) {
#pragma unroll
            for (int mt = 0; mt < 2; mt++) {
                f32x4 acc[4];
#pragma unroll
                for (int nt = 0; nt < 4; nt++) { f32x4 c; c[0]=c[1]=c[2]=c[3]=bb1[nt]; acc[nt]=c; }
#pragma unroll
                for (int s = 0; s < 2; s++) {
#pragma unroll
                    for (int nt = 0; nt < 4; nt++)
                        acc[nt] = __builtin_amdgcn_mfma_f32_16x16x32_f16(a1[ab + mt][s], bw1[nt][s], acc[nt], 0, 0, 0);
                }
                unsigned* sl = (unsigned*)slab;
#pragma unroll
                for (int nt = 0; nt < 4; nt++) {
                    float v0 = fmaxf(acc[nt][0], 0.0f), v1 = fmaxf(acc[nt][1], 0.0f);
                    float v2 = fmaxf(acc[nt][2], 0.0f), v3 = fmaxf(acc[nt][3], 0.0f);
                    float t0_ = dppmov<DPP_SWAP>(v0), t1_ = dppmov<DPP_SWAP>(v1);
                    float t2_ = dppmov<DPP_SWAP>(v2), t3_ = dppmov<DPP_SWAP>(v3);
                    unsigned u0 = pkrtz(odd ? t2_ : v0, odd ? v2 : t0_);
                    unsigned u1 = pkrtz(odd ? t3_ : v1, odd ? v3 : t1_);
                    int rowA = 16 * mt + 4 * q + (odd ? 2 : 0);
                    int c    = 2 * nt + (n >> 3);
                    int a0   = (rowA * 8 + (c ^ ((rowA >> 1) & 7))) * 4 + ((n >> 1) & 3);
                    sl[a0] = u0; sl[a0 + 32] = u1;
                }
            }
        };

        // ---- stage 2: layer-2 slab -> slab (in-place; same-wave DS ops are in-order) ----
        auto stage_L2 = [&](char* slab) {
#pragma unroll
            for (int mt = 0; mt < 2; mt++) {
                const int M0 = 16 * mt;
                f32x4 acc[4];
#pragma unroll
                for (int nt = 0; nt < 4; nt++) { f32x4 c; c[0]=c[1]=c[2]=c[3]=bb2[nt]; acc[nt]=c; }
#pragma unroll
                for (int s = 0; s < 2; s++) {
                    half8 a = *(const half8*)(slab + ((M0 + n) * 8 + ((s * 4 + q) ^ swr)) * 16);
#pragma unroll
                    for (int nt = 0; nt < 4; nt++)
                        acc[nt] = __builtin_amdgcn_mfma_f32_16x16x32_f16(a, bw2[nt][s], acc[nt], 0, 0, 0);
                }
                unsigned* sl = (unsigned*)slab;
#pragma unroll
                for (int nt = 0; nt < 4; nt++) {
                    float v0 = fmaxf(acc[nt][0], 0.0f), v1 = fmaxf(acc[nt][1], 0.0f);
                    float v2 = fmaxf(acc[nt][2], 0.0f), v3 = fmaxf(acc[nt][3], 0.0f);
                    float t0_ = dppmov<DPP_SWAP>(v0), t1_ = dppmov<DPP_SWAP>(v1);
                    float t2_ = dppmov<DPP_SWAP>(v2), t3_ = dppmov<DPP_SWAP>(v3);
                    unsigned u0 = pkrtz(odd ? t2_ : v0, odd ? v2 : t0_);
                    unsigned u1 = pkrtz(odd ? t3_ : v1, odd ? v3 : t1_);
                    int rowA = M0 + 4 * q + (odd ? 2 : 0);
                    int c    = 2 * nt + (n >> 3);
                    int a0   = (rowA * 8 + (c ^ ((rowA >> 1) & 7))) * 4 + ((n >> 1) & 3);
                    sl[a0] = u0; sl[a0 + 32] = u1;
                }
            }
        };

        // ---- stage 3: layers 3+4 slab -> scores ----
        auto stage_L34 = [&](char* slab, int rbb) {
#pragma unroll
            for (int mt = 0; mt < 2; mt++) {
                const int M0 = 16 * mt;
                f32x4 acc[2];
#pragma unroll
                for (int nt = 0; nt < 2; nt++) { f32x4 c; c[0]=c[1]=c[2]=c[3]=bb3[nt]; acc[nt]=c; }
#pragma unroll
                for (int s = 0; s < 2; s++) {
                    half8 a = *(const half8*)(slab + ((M0 + n) * 8 + ((s * 4 + q) ^ swr)) * 16);
#pragma unroll
                    for (int nt = 0; nt < 2; nt++)
                        acc[nt] = __builtin_amdgcn_mfma_f32_16x16x32_f16(a, bw3[nt][s], acc[nt], 0, 0, 0);
                }
                f32x4 red;
#pragma unroll
                for (int r = 0; r < 4; r++)
                    red[r] = fmaxf(acc[0][r], 0.0f) * w4a + fmaxf(acc[1][r], 0.0f) * w4b;
#pragma unroll
                for (int r = 0; r < 4; r++) {
                    red[r] += dppmov<0x121>(red[r]);   // row_ror:1
                    red[r] += dppmov<0x122>(red[r]);   // row_ror:2
                    red[r] += dppmov<0x124>(red[r]);   // row_ror:4
                    red[r] += dppmov<0x128>(red[r]);   // row_ror:8
                }
                int t = rbb + M0 + q * 4 + n;
                float val = (n == 0) ? red[0] : (n == 1) ? red[1] : (n == 2) ? red[2] : red[3];
                if (n < 4 && t < T) out[t] = val + b4v;
            }
        };

        for (int rb = r0; rb < rend; rb += 64) {
            // ---- refill job-start window when it may not cover [rb, rb+64) ----
            // post-advance invariant: jstart(j_lo+1) > rb  =>  jstart(j_lo+64) >= rb+64,
            // so every row <= rb+63 resolves inside the 64-job window.
            if (win_top <= rb + 63) {
                for (;;) {
                    int jj = j_lo + lane;
                    sreg = (jj < J) ? (boffs[jj >> 8] + (jsv[jj] >> 6)) : 0x7fffffff;
                    unsigned long long m = __ballot(sreg <= rb);
                    int adv = 63 - __builtin_clzll(m);   // bit0 always set (invariant)
                    j_lo += adv;
                    if (adv == 0) break;
                }
                swin[wv][lane] = sreg;
                win_top = __shfl(sreg, 63);
            }

            // ---- full-wave per-row search: lane resolves row rb+lane ----
            {
                int rt = rb + lane;
                const int* sw = swin[wv];
                int lj = 0;
#pragma unroll
                for (int stp = 32; stp; stp >>= 1) {
                    int c2 = lj + stp;
                    if (c2 < 64 && sw[c2] <= rt) lj = c2;
                }
                srow[wv][lane] = (lj << 8) | (rt - sw[lj]);   // exec fits 8 bits
            }
            // same-wave LDS: DS pipe is in-order, no barrier needed

            // ---- A1 fragments for ALL 4 m-tiles issued together ----
#pragma unroll
            for (int mt = 0; mt < 4; mt++) {
                int  rt    = rb + 16 * mt + n;
                bool valid = rt < T;
                int  u     = srow[wv][16 * mt + n];
                int  jj2   = j_lo + (u >> 8);
                const uint4* fsrc = (const uint4*)(feat + (size_t)jj2 * 20);
                uint4 g0 = fsrc[q];
                a1[mt][0] = __builtin_bit_cast(half8, g0);
                uint4 g1 = make_uint4(0, 0, 0, 0);
                if (q == 0) {
                    g1 = fsrc[4];
                    float fe = valid ? (float)(u & 255) * 0.02f : 0.0f;  // exec_act_idx == rt - jstart
                    g1.y = (g1.y & 0xffffu) | ((unsigned)h2u((_Float16)fe) << 16);
                }
                a1[mt][1] = __builtin_bit_cast(half8, g1);
            }

            // ---- 2-deep software pipeline: B's compute hides A's LDS round-trips and vice versa ----
            const bool hasB = (rb + 32 < rend);
            stage_L1(slabA, 0);
            if (hasB) stage_L1(slabB, 2);
            stage_L2(slabA);
            if (hasB) stage_L2(slabB);
            stage_L34(slabA, rb);
            if (hasB) stage_L34(slabB, rb + 32);
        }
    }
}

extern "C" void kernel_launch(void* const* d_in, const int* in_sizes, int n_in,
                              void* d_out, int out_size, void* d_ws, size_t ws_size,
                              hipStream_t stream)
{
    const float* x             = (const float*)d_in[0];
    const float* h_dag         = (const float*)d_in[1];
    const float* h_glob        = (const float*)d_in[2];
    const int*   ptr           = (const int*)d_in[3];
    const int*   job_indices   = (const int*)d_in[4];
    const int*   num_exec_acts = (const int*)d_in[5];
    const float* W1 = (const float*)d_in[7];
    const float* b1 = (const float*)d_in[8];
    const float* W2 = (const float*)d_in[9];
    const float* b2 = (const float*)d_in[10];
    const float* W3 = (const float*)d_in[11];
    const float* b3 = (const float*)d_in[12];
    const float* W4 = (const float*)d_in[13];
    const float* b4 = (const float*)d_in[14];
    float* out = (float*)d_out;

    int J  = in_sizes[4];
    int T  = in_sizes[6];
    int nb = (J + TPB - 1) / TPB;

    // workspace layout
    char* wsp = (char*)d_ws;
    int* bsum = (int*)wsp;
    wsp += (((size_t)nb * 4) + 255) / 256 * 256;
    int* jsv = (int*)wsp;
    wsp += (((size_t)J * 4) + 255) / 256 * 256;
    uint4* wfrag = (uint4*)wsp;            // 20*64*16 B
    wsp += 20 * 64 * 16;
    float4* bfrag = (float4*)wsp;          // 3*64*16 B
    wsp += 3 * 64 * 16;
    unsigned int* feat = (unsigned int*)wsp;   // J*20 words

    k_prep<<<nb + 1, TPB, 0, stream>>>(x, h_dag, h_glob, ptr, job_indices, num_exec_acts,
                                       J, nb, feat, bsum, jsv,
                                       W1, b1, W2, b2, W3, b3, W4, wfrag, bfrag);

    int numTiles = (T + 127) / 128;
    int grid = numTiles < 1280 ? numTiles : 1280;
    int chunk = (numTiles + grid - 1) / grid;
    grid = (numTiles + chunk - 1) / chunk;
    k_mlp_mfma<<<grid, TPB, 0, stream>>>(feat, jsv, bsum, wfrag, bfrag, b4,
                                         out, T, J, nb, numTiles, chunk);
}

// Round 7
// 171.723 us; speedup vs baseline: 1.6739x; 1.0210x over previous
//
#include <hip/hip_runtime.h>

#define TPB 256

using half8  = __attribute__((ext_vector_type(8))) _Float16;
using fp16x2 = __attribute__((ext_vector_type(2))) __fp16;
using f32x4  = __attribute__((ext_vector_type(4))) float;

static __device__ __forceinline__ unsigned pkrtz(float a, float b) {
    fp16x2 h = __builtin_amdgcn_cvt_pkrtz(a, b);
    return __builtin_bit_cast(unsigned, h);
}
template <int CTRL>
static __device__ __forceinline__ float dppmov(float x) {
    return __int_as_float(__builtin_amdgcn_mov_dpp(__float_as_int(x), CTRL, 0xF, 0xF, true));
}
#define DPP_SWAP 0xB1   // quad_perm [1,0,3,2]

// ---------- kernel 1: per-JOB shared L1 (s_j = W1[0:35]^T f_shared + b1) + scan; extra block: weight frags ----------
__global__ __launch_bounds__(TPB) void k_prep(const float* __restrict__ x,
                                              const float* __restrict__ h_dag,
                                              const float* __restrict__ h_glob,
                                              const int* __restrict__ ptr,
                                              const int* __restrict__ job_indices,
                                              const int* __restrict__ num_exec_acts,
                                              int J, int nb,
                                              float* __restrict__ s_tab,
                                              int* __restrict__ bsum, int* __restrict__ jsv,
                                              const float* __restrict__ W1,
                                              const float* __restrict__ b1,
                                              const float* __restrict__ W2,
                                              const float* __restrict__ b2,
                                              const float* __restrict__ W3,
                                              const float* __restrict__ b3,
                                              const float* __restrict__ W4,
                                              uint4* __restrict__ wfrag,
                                              float4* __restrict__ bfrag)
{
    if (blockIdx.x == (unsigned)nb) {
        // ---- weight/bias fragment build (L2/L3 only; L1 handled via s-table) ----
        if (threadIdx.x < 64) {
            int lane = threadIdx.x;
            int n = lane & 15, q = lane >> 4;
#pragma unroll
            for (int nt = 0; nt < 4; nt++) {
#pragma unroll
                for (int s = 0; s < 2; s++) {
                    half8 w2f;
#pragma unroll
                    for (int jj = 0; jj < 8; jj++) {
                        int ks = s * 32 + q * 8 + jj;
                        w2f[jj] = (_Float16)W2[ks * 64 + nt * 16 + n];
                    }
                    wfrag[(8 + nt * 2 + s) * 64 + lane] = __builtin_bit_cast(uint4, w2f);
                }
            }
#pragma unroll
            for (int nt = 0; nt < 2; nt++) {
#pragma unroll
                for (int s = 0; s < 2; s++) {
                    half8 w3f;
#pragma unroll
                    for (int jj = 0; jj < 8; jj++) {
                        int ks = s * 32 + q * 8 + jj;
                        w3f[jj] = (_Float16)W3[ks * 32 + nt * 16 + n];
                    }
                    wfrag[(16 + nt * 2 + s) * 64 + lane] = __builtin_bit_cast(uint4, w3f);
                }
            }
            bfrag[1 * 64 + lane] = make_float4(b2[n], b2[16 + n], b2[32 + n], b2[48 + n]);
            bfrag[2 * 64 + lane] = make_float4(b3[n], b3[16 + n], W4[n], W4[16 + n]);
        }
        return;
    }

    __shared__ int sc[TPB];
    int j = blockIdx.x * TPB + threadIdx.x;
    int v = 0;
    if (j < J) {
        int ji   = job_indices[j];
        v        = num_exec_acts[ji];
        int node = ptr[ji];
        float f[35];
        f[0] = x[node * 5 + 0];
        f[1] = x[node * 5 + 1];
        f[2] = x[node * 5 + 2];
        float4 hd[4], hg[4];
#pragma unroll
        for (int c4 = 0; c4 < 4; c4++) hd[c4] = *(const float4*)(h_dag + (size_t)ji * 16 + 4 * c4);
#pragma unroll
        for (int c4 = 0; c4 < 4; c4++) hg[c4] = *(const float4*)(h_glob + (size_t)j * 16 + 4 * c4);
#pragma unroll
        for (int c4 = 0; c4 < 4; c4++) {
            f[3 + 4 * c4 + 0]  = hd[c4].x; f[3 + 4 * c4 + 1]  = hd[c4].y;
            f[3 + 4 * c4 + 2]  = hd[c4].z; f[3 + 4 * c4 + 3]  = hd[c4].w;
            f[19 + 4 * c4 + 0] = hg[c4].x; f[19 + 4 * c4 + 1] = hg[c4].y;
            f[19 + 4 * c4 + 2] = hg[c4].z; f[19 + 4 * c4 + 3] = hg[c4].w;
        }
        // s_j = b1 + sum_{c<35} f[c] * W1[c][:]   (W1 rows uniform across lanes -> scalar-cached)
        float acc[64];
#pragma unroll
        for (int d4 = 0; d4 < 16; d4++) {
            float4 b = *(const float4*)(b1 + 4 * d4);
            acc[4 * d4 + 0] = b.x; acc[4 * d4 + 1] = b.y;
            acc[4 * d4 + 2] = b.z; acc[4 * d4 + 3] = b.w;
        }
#pragma unroll
        for (int c = 0; c < 35; c++) {
            float fc = f[c];
#pragma unroll
            for (int d4 = 0; d4 < 16; d4++) {
                float4 w = *(const float4*)(W1 + c * 64 + 4 * d4);
                acc[4 * d4 + 0] += fc * w.x; acc[4 * d4 + 1] += fc * w.y;
                acc[4 * d4 + 2] += fc * w.z; acc[4 * d4 + 3] += fc * w.w;
            }
        }
        float4* sd = (float4*)(s_tab + (size_t)j * 64);
#pragma unroll
        for (int d4 = 0; d4 < 16; d4++)
            sd[d4] = make_float4(acc[4 * d4], acc[4 * d4 + 1], acc[4 * d4 + 2], acc[4 * d4 + 3]);
    }
    // inclusive scan of v
    sc[threadIdx.x] = v;
    __syncthreads();
    for (int d = 1; d < TPB; d <<= 1) {
        int add = (threadIdx.x >= d) ? sc[threadIdx.x - d] : 0;
        __syncthreads();
        sc[threadIdx.x] += add;
        __syncthreads();
    }
    if (j < J) jsv[j] = ((sc[threadIdx.x] - v) << 6) | v;
    if (threadIdx.x == TPB - 1) bsum[blockIdx.x] = sc[TPB - 1];
}

// ---------- kernel 2: MLP from s-table; h1 = ReLU(s + e*w36) built in registers in MFMA A-layout ----------
__global__ __launch_bounds__(TPB) void k_mlp_mfma(const float* __restrict__ s_tab,
                                                  const float* __restrict__ W1,
                                                  const int* __restrict__ jsv,
                                                  const int* __restrict__ bsum,
                                                  const uint4* __restrict__ wfrag,
                                                  const float4* __restrict__ bfrag,
                                                  const float* __restrict__ b4,
                                                  float* __restrict__ out,
                                                  int T, int J, int nb, int numTiles, int chunk)
{
    __shared__ __align__(16) char smem[4 * 4096];   // one 4 KB slab per wave (h2 staging only)
    __shared__ int boffs[TPB];                       // exclusive scan of bsum
    __shared__ int swin[4][64];                      // per-wave job-start window
    __shared__ int srow[4][64];                      // per-wave per-row (job<<8|exec) for 64 rows
    const int tid  = threadIdx.x;
    const int lane = tid & 63;
    const int wv   = tid >> 6;
    const int n    = lane & 15;
    const int q    = lane >> 4;
    char* slab = smem + wv * 4096;

    // ---- block-local exclusive scan of bsum (nb <= 256) ----
    {
        int v = (tid < nb) ? bsum[tid] : 0;
        boffs[tid] = v;
        __syncthreads();
        for (int d = 1; d < TPB; d <<= 1) {
            int add = (tid >= d) ? boffs[tid - d] : 0;
            __syncthreads();
            boffs[tid] += add;
            __syncthreads();
        }
        int ex = boffs[tid] - v;
        __syncthreads();
        boffs[tid] = ex;
        __syncthreads();
    }

    // ---- fragment loads: L2/L3 weights + biases ----
    half8 bw2[4][2], bw3[2][2];
#pragma unroll
    for (int nt = 0; nt < 4; nt++)
#pragma unroll
        for (int s = 0; s < 2; s++)
            bw2[nt][s] = __builtin_bit_cast(half8, wfrag[(8 + nt * 2 + s) * 64 + lane]);
#pragma unroll
    for (int nt = 0; nt < 2; nt++)
#pragma unroll
        for (int s = 0; s < 2; s++)
            bw3[nt][s] = __builtin_bit_cast(half8, wfrag[(16 + nt * 2 + s) * 64 + lane]);

    float4 bf2 = bfrag[1 * 64 + lane];
    float4 bf3 = bfrag[2 * 64 + lane];
    float bb2[4] = {bf2.x, bf2.y, bf2.z, bf2.w};
    float bb3[2] = {bf3.x, bf3.y};
    const float w4a = bf3.z, w4b = bf3.w;
    const float b4v = b4[0];
    const int   swr = (n >> 1) & 7;
    const int   odd = n & 1;

    // ---- per-lane w36 slice: dims {q*8..q*8+7} and {32+q*8..32+q*8+7} of W1 row 35 ----
    float w36[16];
    {
        const float* wp = W1 + 35 * 64 + q * 8;
        float4 wa0 = *(const float4*)(wp);
        float4 wa1 = *(const float4*)(wp + 4);
        float4 wb0 = *(const float4*)(wp + 32);
        float4 wb1 = *(const float4*)(wp + 36);
        w36[0]=wa0.x; w36[1]=wa0.y; w36[2]=wa0.z; w36[3]=wa0.w;
        w36[4]=wa1.x; w36[5]=wa1.y; w36[6]=wa1.z; w36[7]=wa1.w;
        w36[8]=wb0.x; w36[9]=wb0.y; w36[10]=wb0.z; w36[11]=wb0.w;
        w36[12]=wb1.x; w36[13]=wb1.y; w36[14]=wb1.z; w36[15]=wb1.w;
    }

    // ---- per-block contiguous tile range; wave wv owns the wv-th quarter (contiguous rows) ----
    const int t0 = blockIdx.x * chunk;
    const int t1 = (t0 + chunk < numTiles) ? (t0 + chunk) : numTiles;
    const int R  = (t1 - t0) * 32;
    const int r0 = t0 * 128 + wv * R;
    int rend = r0 + R;
    if (rend > T) rend = T;

    if (r0 < rend) {
        int j_lo;
        {
            int lo = 0, hi = nb - 1;
            while (lo < hi) {
                int mid = (lo + hi + 1) >> 1;
                if (boffs[mid] <= r0) lo = mid; else hi = mid - 1;
            }
            j_lo = lo << 8;
        }
        int sreg    = 0;
        int win_top = 0x80000000;

        half8 a2[2][2];   // L2 A-fragments for one 32-row half, built in registers

        // ---- h1 build: rows 16*(mtbase+m)+n, m=0,1; output straight into a2 in A-frag layout ----
        auto build_a2 = [&](int mtbase) {
#pragma unroll
            for (int m = 0; m < 2; m++) {
                int u   = srow[wv][16 * (mtbase + m) + n];
                int job = j_lo + (u >> 8);
                if (job > J - 1) job = J - 1;
                float e = (float)(u & 255) * 0.02f;
                const float* sp = s_tab + (size_t)job * 64 + q * 8;
                float4 s0 = *(const float4*)(sp);
                float4 s1 = *(const float4*)(sp + 4);
                float4 s2 = *(const float4*)(sp + 32);
                float4 s3 = *(const float4*)(sp + 36);
                float h[16];
                h[0]  = fmaxf(s0.x + e * w36[0],  0.0f); h[1]  = fmaxf(s0.y + e * w36[1],  0.0f);
                h[2]  = fmaxf(s0.z + e * w36[2],  0.0f); h[3]  = fmaxf(s0.w + e * w36[3],  0.0f);
                h[4]  = fmaxf(s1.x + e * w36[4],  0.0f); h[5]  = fmaxf(s1.y + e * w36[5],  0.0f);
                h[6]  = fmaxf(s1.z + e * w36[6],  0.0f); h[7]  = fmaxf(s1.w + e * w36[7],  0.0f);
                h[8]  = fmaxf(s2.x + e * w36[8],  0.0f); h[9]  = fmaxf(s2.y + e * w36[9],  0.0f);
                h[10] = fmaxf(s2.z + e * w36[10], 0.0f); h[11] = fmaxf(s2.w + e * w36[11], 0.0f);
                h[12] = fmaxf(s3.x + e * w36[12], 0.0f); h[13] = fmaxf(s3.y + e * w36[13], 0.0f);
                h[14] = fmaxf(s3.z + e * w36[14], 0.0f); h[15] = fmaxf(s3.w + e * w36[15], 0.0f);
                a2[m][0] = __builtin_bit_cast(half8, make_uint4(pkrtz(h[0], h[1]),  pkrtz(h[2], h[3]),
                                                                pkrtz(h[4], h[5]),  pkrtz(h[6], h[7])));
                a2[m][1] = __builtin_bit_cast(half8, make_uint4(pkrtz(h[8], h[9]),  pkrtz(h[10], h[11]),
                                                                pkrtz(h[12], h[13]), pkrtz(h[14], h[15])));
            }
        };

        // ---- layer 2 from register A-frags -> repack -> slab ----
        auto stage_L2r = [&]() {
#pragma unroll
            for (int mt = 0; mt < 2; mt++) {
                f32x4 acc[4];
#pragma unroll
                for (int nt = 0; nt < 4; nt++) { f32x4 c; c[0]=c[1]=c[2]=c[3]=bb2[nt]; acc[nt]=c; }
#pragma unroll
                for (int s = 0; s < 2; s++) {
#pragma unroll
                    for (int nt = 0; nt < 4; nt++)
                        acc[nt] = __builtin_amdgcn_mfma_f32_16x16x32_f16(a2[mt][s], bw2[nt][s], acc[nt], 0, 0, 0);
                }
                unsigned* sl = (unsigned*)slab;
#pragma unroll
                for (int nt = 0; nt < 4; nt++) {
                    float v0 = fmaxf(acc[nt][0], 0.0f), v1 = fmaxf(acc[nt][1], 0.0f);
                    float v2 = fmaxf(acc[nt][2], 0.0f), v3 = fmaxf(acc[nt][3], 0.0f);
                    float t0_ = dppmov<DPP_SWAP>(v0), t1_ = dppmov<DPP_SWAP>(v1);
                    float t2_ = dppmov<DPP_SWAP>(v2), t3_ = dppmov<DPP_SWAP>(v3);
                    unsigned u0 = pkrtz(odd ? t2_ : v0, odd ? v2 : t0_);
                    unsigned u1 = pkrtz(odd ? t3_ : v1, odd ? v3 : t1_);
                    int rowA = 16 * mt + 4 * q + (odd ? 2 : 0);
                    int c    = 2 * nt + (n >> 3);
                    int a0   = (rowA * 8 + (c ^ ((rowA >> 1) & 7))) * 4 + ((n >> 1) & 3);
                    sl[a0] = u0; sl[a0 + 32] = u1;
                }
            }
        };

        // ---- layers 3+4: slab -> scores ----
        auto stage_L34 = [&](int rbb) {
#pragma unroll
            for (int mt = 0; mt < 2; mt++) {
                const int M0 = 16 * mt;
                f32x4 acc[2];
#pragma unroll
                for (int nt = 0; nt < 2; nt++) { f32x4 c; c[0]=c[1]=c[2]=c[3]=bb3[nt]; acc[nt]=c; }
#pragma unroll
                for (int s = 0; s < 2; s++) {
                    half8 a = *(const half8*)(slab + ((M0 + n) * 8 + ((s * 4 + q) ^ swr)) * 16);
#pragma unroll
                    for (int nt = 0; nt < 2; nt++)
                        acc[nt] = __builtin_amdgcn_mfma_f32_16x16x32_f16(a, bw3[nt][s], acc[nt], 0, 0, 0);
                }
                f32x4 red;
#pragma unroll
                for (int r = 0; r < 4; r++)
                    red[r] = fmaxf(acc[0][r], 0.0f) * w4a + fmaxf(acc[1][r], 0.0f) * w4b;
#pragma unroll
                for (int r = 0; r < 4; r++) {
                    red[r] += dppmov<0x121>(red[r]);   // row_ror:1
                    red[r] += dppmov<0x122>(red[r]);   // row_ror:2
                    red[r] += dppmov<0x124>(red[r]);   // row_ror:4
                    red[r] += dppmov<0x128>(red[r]);   // row_ror:8
                }
                int t = rbb + M0 + q * 4 + n;
                float val = (n == 0) ? red[0] : (n == 1) ? red[1] : (n == 2) ? red[2] : red[3];
                if (n < 4 && t < T) out[t] = val + b4v;
            }
        };

        for (int rb = r0; rb < rend; rb += 64) {
            // ---- refill job-start window when it may not cover [rb, rb+64) ----
            if (win_top <= rb + 63) {
                for (;;) {
                    int jj = j_lo + lane;
                    sreg = (jj < J) ? (boffs[jj >> 8] + (jsv[jj] >> 6)) : 0x7fffffff;
                    unsigned long long m = __ballot(sreg <= rb);
                    int adv = 63 - __builtin_clzll(m);
                    j_lo += adv;
                    if (adv == 0) break;
                }
                swin[wv][lane] = sreg;
                win_top = __shfl(sreg, 63);
            }

            // ---- full-wave per-row search: lane resolves row rb+lane ----
            {
                int rt = rb + lane;
                const int* sw = swin[wv];
                int lj = 0;
#pragma unroll
                for (int stp = 32; stp; stp >>= 1) {
                    int c2 = lj + stp;
                    if (c2 < 64 && sw[c2] <= rt) lj = c2;
                }
                srow[wv][lane] = (lj << 8) | (rt - sw[lj]);
            }
            // same-wave LDS: DS pipe is in-order, no barrier needed

            build_a2(0);
            stage_L2r();
            stage_L34(rb);
            if (rb + 32 < rend) {
                build_a2(2);
                stage_L2r();
                stage_L34(rb + 32);
            }
        }
    }
}

extern "C" void kernel_launch(void* const* d_in, const int* in_sizes, int n_in,
                              void* d_out, int out_size, void* d_ws, size_t ws_size,
                              hipStream_t stream)
{
    const float* x             = (const float*)d_in[0];
    const float* h_dag         = (const float*)d_in[1];
    const float* h_glob        = (const float*)d_in[2];
    const int*   ptr           = (const int*)d_in[3];
    const int*   job_indices   = (const int*)d_in[4];
    const int*   num_exec_acts = (const int*)d_in[5];
    const float* W1 = (const float*)d_in[7];
    const float* b1 = (const float*)d_in[8];
    const float* W2 = (const float*)d_in[9];
    const float* b2 = (const float*)d_in[10];
    const float* W3 = (const float*)d_in[11];
    const float* b3 = (const float*)d_in[12];
    const float* W4 = (const float*)d_in[13];
    const float* b4 = (const float*)d_in[14];
    float* out = (float*)d_out;

    int J  = in_sizes[4];
    int T  = in_sizes[6];
    int nb = (J + TPB - 1) / TPB;

    // workspace layout
    char* wsp = (char*)d_ws;
    int* bsum = (int*)wsp;
    wsp += (((size_t)nb * 4) + 255) / 256 * 256;
    int* jsv = (int*)wsp;
    wsp += (((size_t)J * 4) + 255) / 256 * 256;
    uint4* wfrag = (uint4*)wsp;            // 20*64*16 B
    wsp += 20 * 64 * 16;
    float4* bfrag = (float4*)wsp;          // 3*64*16 B
    wsp += 3 * 64 * 16;
    float* s_tab = (float*)wsp;            // J*64 f32 (per-job shared L1 pre-activation)

    k_prep<<<nb + 1, TPB, 0, stream>>>(x, h_dag, h_glob, ptr, job_indices, num_exec_acts,
                                       J, nb, s_tab, bsum, jsv,
                                       W1, b1, W2, b2, W3, b3, W4, wfrag, bfrag);

    int numTiles = (T + 127) / 128;
    int grid = numTiles < 1280 ? numTiles : 1280;
    int chunk = (numTiles + grid - 1) / grid;
    grid = (numTiles + chunk - 1) / chunk;
    k_mlp_mfma<<<grid, TPB, 0, stream>>>(s_tab, W1, jsv, bsum, wfrag, bfrag, b4,
                                         out, T, J, nb, numTiles, chunk);
}

// Round 8
// 153.945 us; speedup vs baseline: 1.8672x; 1.1155x over previous
//
#include <hip/hip_runtime.h>

#define TPB 256

using half8  = __attribute__((ext_vector_type(8))) _Float16;
using fp16x2 = __attribute__((ext_vector_type(2))) __fp16;
using hv2    = __attribute__((ext_vector_type(2))) _Float16;
using f32x4  = __attribute__((ext_vector_type(4))) float;

static __device__ __forceinline__ unsigned pkrtz(float a, float b) {
    fp16x2 h = __builtin_amdgcn_cvt_pkrtz(a, b);
    return __builtin_bit_cast(unsigned, h);
}
static __device__ __forceinline__ hv2 pk2(float a, float b) {
    fp16x2 h = __builtin_amdgcn_cvt_pkrtz(a, b);
    return __builtin_bit_cast(hv2, h);
}
template <int CTRL>
static __device__ __forceinline__ float dppmov(float x) {
    return __int_as_float(__builtin_amdgcn_mov_dpp(__float_as_int(x), CTRL, 0xF, 0xF, true));
}
#define DPP_SWAP 0xB1   // quad_perm [1,0,3,2]

// ---------- kernel 1: per-JOB shared L1 via 4-way split matvec (f16 s-table) + scan; last block: weight frags ----------
// grid = 4*nb + 1. Block c < 4*nb: quarter qtr = c/nb computes dims [qtr*16, qtr*16+16) for jobs of block c%nb.
// Only qtr==0 blocks run the scan. s16 layout: [qtr][job][16 f16] (32 B per (qtr,job)) -> coalesced stores.
__global__ __launch_bounds__(TPB) void k_prep(const float* __restrict__ x,
                                              const float* __restrict__ h_dag,
                                              const float* __restrict__ h_glob,
                                              const int* __restrict__ ptr,
                                              const int* __restrict__ job_indices,
                                              const int* __restrict__ num_exec_acts,
                                              int J, int nb,
                                              unsigned* __restrict__ s16,
                                              int* __restrict__ bsum, int* __restrict__ jsv,
                                              const float* __restrict__ W1,
                                              const float* __restrict__ b1,
                                              const float* __restrict__ W2,
                                              const float* __restrict__ b2,
                                              const float* __restrict__ W3,
                                              const float* __restrict__ b3,
                                              const float* __restrict__ W4,
                                              uint4* __restrict__ wfrag,
                                              float4* __restrict__ bfrag)
{
    if (blockIdx.x == (unsigned)(4 * nb)) {
        // ---- weight/bias fragment build (L2/L3 only) ----
        if (threadIdx.x < 64) {
            int lane = threadIdx.x;
            int n = lane & 15, q = lane >> 4;
#pragma unroll
            for (int nt = 0; nt < 4; nt++) {
#pragma unroll
                for (int s = 0; s < 2; s++) {
                    half8 w2f;
#pragma unroll
                    for (int jj = 0; jj < 8; jj++) {
                        int ks = s * 32 + q * 8 + jj;
                        w2f[jj] = (_Float16)W2[ks * 64 + nt * 16 + n];
                    }
                    wfrag[(8 + nt * 2 + s) * 64 + lane] = __builtin_bit_cast(uint4, w2f);
                }
            }
#pragma unroll
            for (int nt = 0; nt < 2; nt++) {
#pragma unroll
                for (int s = 0; s < 2; s++) {
                    half8 w3f;
#pragma unroll
                    for (int jj = 0; jj < 8; jj++) {
                        int ks = s * 32 + q * 8 + jj;
                        w3f[jj] = (_Float16)W3[ks * 32 + nt * 16 + n];
                    }
                    wfrag[(16 + nt * 2 + s) * 64 + lane] = __builtin_bit_cast(uint4, w3f);
                }
            }
            bfrag[1 * 64 + lane] = make_float4(b2[n], b2[16 + n], b2[32 + n], b2[48 + n]);
            bfrag[2 * 64 + lane] = make_float4(b3[n], b3[16 + n], W4[n], W4[16 + n]);
        }
        return;
    }

    const int qtr = blockIdx.x / nb;        // 0..3
    const int cb  = blockIdx.x - qtr * nb;  // job block
    int j = cb * TPB + threadIdx.x;
    int v = 0;
    if (j < J) {
        int ji   = job_indices[j];
        if (qtr == 0) v = num_exec_acts[ji];
        int node = ptr[ji];
        float f[35];
        f[0] = x[node * 5 + 0];
        f[1] = x[node * 5 + 1];
        f[2] = x[node * 5 + 2];
        float4 hd[4], hg[4];
#pragma unroll
        for (int c4 = 0; c4 < 4; c4++) hd[c4] = *(const float4*)(h_dag + (size_t)ji * 16 + 4 * c4);
#pragma unroll
        for (int c4 = 0; c4 < 4; c4++) hg[c4] = *(const float4*)(h_glob + (size_t)j * 16 + 4 * c4);
#pragma unroll
        for (int c4 = 0; c4 < 4; c4++) {
            f[3 + 4 * c4 + 0]  = hd[c4].x; f[3 + 4 * c4 + 1]  = hd[c4].y;
            f[3 + 4 * c4 + 2]  = hd[c4].z; f[3 + 4 * c4 + 3]  = hd[c4].w;
            f[19 + 4 * c4 + 0] = hg[c4].x; f[19 + 4 * c4 + 1] = hg[c4].y;
            f[19 + 4 * c4 + 2] = hg[c4].z; f[19 + 4 * c4 + 3] = hg[c4].w;
        }
        // acc = b1[qtr*16..+16) + sum_c f[c] * W1[c][qtr*16..+16)
        float acc[16];
#pragma unroll
        for (int d4 = 0; d4 < 4; d4++) {
            float4 b = *(const float4*)(b1 + qtr * 16 + 4 * d4);
            acc[4 * d4 + 0] = b.x; acc[4 * d4 + 1] = b.y;
            acc[4 * d4 + 2] = b.z; acc[4 * d4 + 3] = b.w;
        }
#pragma unroll
        for (int c = 0; c < 35; c++) {
            float fc = f[c];
#pragma unroll
            for (int d4 = 0; d4 < 4; d4++) {
                float4 w = *(const float4*)(W1 + c * 64 + qtr * 16 + 4 * d4);
                acc[4 * d4 + 0] += fc * w.x; acc[4 * d4 + 1] += fc * w.y;
                acc[4 * d4 + 2] += fc * w.z; acc[4 * d4 + 3] += fc * w.w;
            }
        }
        // pack to f16 pairs, 32 B contiguous per thread -> coalesced
        unsigned* dst = s16 + ((size_t)qtr * J + j) * 8;
        ((uint4*)dst)[0] = make_uint4(pkrtz(acc[0], acc[1]),  pkrtz(acc[2], acc[3]),
                                      pkrtz(acc[4], acc[5]),  pkrtz(acc[6], acc[7]));
        ((uint4*)dst)[1] = make_uint4(pkrtz(acc[8], acc[9]),  pkrtz(acc[10], acc[11]),
                                      pkrtz(acc[12], acc[13]), pkrtz(acc[14], acc[15]));
    }
    if (qtr != 0) return;

    // inclusive scan of v
    __shared__ int sc[TPB];
    sc[threadIdx.x] = v;
    __syncthreads();
    for (int d = 1; d < TPB; d <<= 1) {
        int add = (threadIdx.x >= d) ? sc[threadIdx.x - d] : 0;
        __syncthreads();
        sc[threadIdx.x] += add;
        __syncthreads();
    }
    if (j < J) jsv[j] = ((sc[threadIdx.x] - v) << 6) | v;
    if (threadIdx.x == TPB - 1) bsum[cb] = sc[TPB - 1];
}

// ---------- kernel 2: MLP from f16 s-table; h1 = ReLU(s + e*w36) via packed f16 math, in A-frag layout ----------
__global__ __launch_bounds__(TPB) void k_mlp_mfma(const unsigned* __restrict__ s16,
                                                  const float* __restrict__ W1,
                                                  const int* __restrict__ jsv,
                                                  const int* __restrict__ bsum,
                                                  const uint4* __restrict__ wfrag,
                                                  const float4* __restrict__ bfrag,
                                                  const float* __restrict__ b4,
                                                  float* __restrict__ out,
                                                  int T, int J, int nb, int numTiles, int chunk)
{
    __shared__ __align__(16) char smem[4 * 4096];   // one 4 KB slab per wave (h2 staging only)
    __shared__ int boffs[TPB];                       // exclusive scan of bsum
    __shared__ int swin[4][64];                      // per-wave job-start window
    __shared__ int srow[4][64];                      // per-wave per-row (job<<8|exec) for 64 rows
    const int tid  = threadIdx.x;
    const int lane = tid & 63;
    const int wv   = tid >> 6;
    const int n    = lane & 15;
    const int q    = lane >> 4;
    char* slab = smem + wv * 4096;

    // ---- block-local exclusive scan of bsum (nb <= 256) ----
    {
        int v = (tid < nb) ? bsum[tid] : 0;
        boffs[tid] = v;
        __syncthreads();
        for (int d = 1; d < TPB; d <<= 1) {
            int add = (tid >= d) ? boffs[tid - d] : 0;
            __syncthreads();
            boffs[tid] += add;
            __syncthreads();
        }
        int ex = boffs[tid] - v;
        __syncthreads();
        boffs[tid] = ex;
        __syncthreads();
    }

    // ---- fragment loads: L2/L3 weights + biases ----
    half8 bw2[4][2], bw3[2][2];
#pragma unroll
    for (int nt = 0; nt < 4; nt++)
#pragma unroll
        for (int s = 0; s < 2; s++)
            bw2[nt][s] = __builtin_bit_cast(half8, wfrag[(8 + nt * 2 + s) * 64 + lane]);
#pragma unroll
    for (int nt = 0; nt < 2; nt++)
#pragma unroll
        for (int s = 0; s < 2; s++)
            bw3[nt][s] = __builtin_bit_cast(half8, wfrag[(16 + nt * 2 + s) * 64 + lane]);

    float4 bf2 = bfrag[1 * 64 + lane];
    float4 bf3 = bfrag[2 * 64 + lane];
    float bb2[4] = {bf2.x, bf2.y, bf2.z, bf2.w};
    float bb3[2] = {bf3.x, bf3.y};
    const float w4a = bf3.z, w4b = bf3.w;
    const float b4v = b4[0];
    const int   swr = (n >> 1) & 7;
    const int   odd = n & 1;

    // ---- per-lane w36 slice as f16 pairs: dims {q*8+2k,q*8+2k+1} and {32+q*8+...} of W1 row 35 ----
    hv2 w36p[8];
    {
        const float* wp = W1 + 35 * 64 + q * 8;
#pragma unroll
        for (int k = 0; k < 4; k++) w36p[k]     = pk2(wp[2 * k],      wp[2 * k + 1]);
#pragma unroll
        for (int k = 0; k < 4; k++) w36p[4 + k] = pk2(wp[32 + 2 * k], wp[32 + 2 * k + 1]);
    }
    const hv2 z2 = {(_Float16)0.0f, (_Float16)0.0f};

    // ---- per-block contiguous tile range; wave wv owns the wv-th quarter (contiguous rows) ----
    const int t0 = blockIdx.x * chunk;
    const int t1 = (t0 + chunk < numTiles) ? (t0 + chunk) : numTiles;
    const int R  = (t1 - t0) * 32;
    const int r0 = t0 * 128 + wv * R;
    int rend = r0 + R;
    if (rend > T) rend = T;

    if (r0 < rend) {
        int j_lo;
        {
            int lo = 0, hi = nb - 1;
            while (lo < hi) {
                int mid = (lo + hi + 1) >> 1;
                if (boffs[mid] <= r0) lo = mid; else hi = mid - 1;
            }
            j_lo = lo << 8;
        }
        int sreg    = 0;
        int win_top = 0x80000000;

        half8 a2[2][2];   // L2 A-fragments for one 32-row half, built in registers

        // ---- h1 build via packed f16: rows 16*(mtbase+m)+n, m=0,1 ----
        auto build_a2 = [&](int mtbase) {
#pragma unroll
            for (int m = 0; m < 2; m++) {
                int u   = srow[wv][16 * (mtbase + m) + n];
                int job = j_lo + (u >> 8);
                if (job > J - 1) job = J - 1;
                float e = (float)(u & 255) * 0.02f;
                hv2 epk = pk2(e, e);
                const uint4* plo = (const uint4*)s16 + ((size_t)(q >> 1) * J + job) * 2 + (q & 1);
                const uint4* phi = (const uint4*)s16 + ((size_t)(2 + (q >> 1)) * J + job) * 2 + (q & 1);
                uint4 lo = *plo;
                uint4 hi = *phi;
                hv2 r0_ = __builtin_elementwise_max(__builtin_bit_cast(hv2, lo.x) + epk * w36p[0], z2);
                hv2 r1_ = __builtin_elementwise_max(__builtin_bit_cast(hv2, lo.y) + epk * w36p[1], z2);
                hv2 r2_ = __builtin_elementwise_max(__builtin_bit_cast(hv2, lo.z) + epk * w36p[2], z2);
                hv2 r3_ = __builtin_elementwise_max(__builtin_bit_cast(hv2, lo.w) + epk * w36p[3], z2);
                a2[m][0] = __builtin_bit_cast(half8, make_uint4(__builtin_bit_cast(unsigned, r0_),
                                                                __builtin_bit_cast(unsigned, r1_),
                                                                __builtin_bit_cast(unsigned, r2_),
                                                                __builtin_bit_cast(unsigned, r3_)));
                hv2 r4_ = __builtin_elementwise_max(__builtin_bit_cast(hv2, hi.x) + epk * w36p[4], z2);
                hv2 r5_ = __builtin_elementwise_max(__builtin_bit_cast(hv2, hi.y) + epk * w36p[5], z2);
                hv2 r6_ = __builtin_elementwise_max(__builtin_bit_cast(hv2, hi.z) + epk * w36p[6], z2);
                hv2 r7_ = __builtin_elementwise_max(__builtin_bit_cast(hv2, hi.w) + epk * w36p[7], z2);
                a2[m][1] = __builtin_bit_cast(half8, make_uint4(__builtin_bit_cast(unsigned, r4_),
                                                                __builtin_bit_cast(unsigned, r5_),
                                                                __builtin_bit_cast(unsigned, r6_),
                                                                __builtin_bit_cast(unsigned, r7_)));
            }
        };

        // ---- layer 2 from register A-frags -> repack -> slab ----
        auto stage_L2r = [&]() {
#pragma unroll
            for (int mt = 0; mt < 2; mt++) {
                f32x4 acc[4];
#pragma unroll
                for (int nt = 0; nt < 4; nt++) { f32x4 c; c[0]=c[1]=c[2]=c[3]=bb2[nt]; acc[nt]=c; }
#pragma unroll
                for (int s = 0; s < 2; s++) {
#pragma unroll
                    for (int nt = 0; nt < 4; nt++)
                        acc[nt] = __builtin_amdgcn_mfma_f32_16x16x32_f16(a2[mt][s], bw2[nt][s], acc[nt], 0, 0, 0);
                }
                unsigned* sl = (unsigned*)slab;
#pragma unroll
                for (int nt = 0; nt < 4; nt++) {
                    float v0 = fmaxf(acc[nt][0], 0.0f), v1 = fmaxf(acc[nt][1], 0.0f);
                    float v2 = fmaxf(acc[nt][2], 0.0f), v3 = fmaxf(acc[nt][3], 0.0f);
                    float t0_ = dppmov<DPP_SWAP>(v0), t1_ = dppmov<DPP_SWAP>(v1);
                    float t2_ = dppmov<DPP_SWAP>(v2), t3_ = dppmov<DPP_SWAP>(v3);
                    unsigned u0 = pkrtz(odd ? t2_ : v0, odd ? v2 : t0_);
                    unsigned u1 = pkrtz(odd ? t3_ : v1, odd ? v3 : t1_);
                    int rowA = 16 * mt + 4 * q + (odd ? 2 : 0);
                    int c    = 2 * nt + (n >> 3);
                    int a0   = (rowA * 8 + (c ^ ((rowA >> 1) & 7))) * 4 + ((n >> 1) & 3);
                    sl[a0] = u0; sl[a0 + 32] = u1;
                }
            }
        };

        // ---- layers 3+4: slab -> scores ----
        auto stage_L34 = [&](int rbb) {
#pragma unroll
            for (int mt = 0; mt < 2; mt++) {
                const int M0 = 16 * mt;
                f32x4 acc[2];
#pragma unroll
                for (int nt = 0; nt < 2; nt++) { f32x4 c; c[0]=c[1]=c[2]=c[3]=bb3[nt]; acc[nt]=c; }
#pragma unroll
                for (int s = 0; s < 2; s++) {
                    half8 a = *(const half8*)(slab + ((M0 + n) * 8 + ((s * 4 + q) ^ swr)) * 16);
#pragma unroll
                    for (int nt = 0; nt < 2; nt++)
                        acc[nt] = __builtin_amdgcn_mfma_f32_16x16x32_f16(a, bw3[nt][s], acc[nt], 0, 0, 0);
                }
                f32x4 red;
#pragma unroll
                for (int r = 0; r < 4; r++)
                    red[r] = fmaxf(acc[0][r], 0.0f) * w4a + fmaxf(acc[1][r], 0.0f) * w4b;
#pragma unroll
                for (int r = 0; r < 4; r++) {
                    red[r] += dppmov<0x121>(red[r]);   // row_ror:1
                    red[r] += dppmov<0x122>(red[r]);   // row_ror:2
                    red[r] += dppmov<0x124>(red[r]);   // row_ror:4
                    red[r] += dppmov<0x128>(red[r]);   // row_ror:8
                }
                int t = rbb + M0 + q * 4 + n;
                float val = (n == 0) ? red[0] : (n == 1) ? red[1] : (n == 2) ? red[2] : red[3];
                if (n < 4 && t < T) out[t] = val + b4v;
            }
        };

        for (int rb = r0; rb < rend; rb += 64) {
            // ---- refill job-start window when it may not cover [rb, rb+64) ----
            if (win_top <= rb + 63) {
                for (;;) {
                    int jj = j_lo + lane;
                    sreg = (jj < J) ? (boffs[jj >> 8] + (jsv[jj] >> 6)) : 0x7fffffff;
                    unsigned long long m = __ballot(sreg <= rb);
                    int adv = 63 - __builtin_clzll(m);
                    j_lo += adv;
                    if (adv == 0) break;
                }
                swin[wv][lane] = sreg;
                win_top = __shfl(sreg, 63);
            }

            // ---- full-wave per-row search: lane resolves row rb+lane ----
            {
                int rt = rb + lane;
                const int* sw = swin[wv];
                int lj = 0;
#pragma unroll
                for (int stp = 32; stp; stp >>= 1) {
                    int c2 = lj + stp;
                    if (c2 < 64 && sw[c2] <= rt) lj = c2;
                }
                srow[wv][lane] = (lj << 8) | (rt - sw[lj]);
            }
            // same-wave LDS: DS pipe is in-order, no barrier needed

            build_a2(0);
            stage_L2r();
            stage_L34(rb);
            if (rb + 32 < rend) {
                build_a2(2);
                stage_L2r();
                stage_L34(rb + 32);
            }
        }
    }
}

extern "C" void kernel_launch(void* const* d_in, const int* in_sizes, int n_in,
                              void* d_out, int out_size, void* d_ws, size_t ws_size,
                              hipStream_t stream)
{
    const float* x             = (const float*)d_in[0];
    const float* h_dag         = (const float*)d_in[1];
    const float* h_glob        = (const float*)d_in[2];
    const int*   ptr           = (const int*)d_in[3];
    const int*   job_indices   = (const int*)d_in[4];
    const int*   num_exec_acts = (const int*)d_in[5];
    const float* W1 = (const float*)d_in[7];
    const float* b1 = (const float*)d_in[8];
    const float* W2 = (const float*)d_in[9];
    const float* b2 = (const float*)d_in[10];
    const float* W3 = (const float*)d_in[11];
    const float* b3 = (const float*)d_in[12];
    const float* W4 = (const float*)d_in[13];
    const float* b4 = (const float*)d_in[14];
    float* out = (float*)d_out;

    int J  = in_sizes[4];
    int T  = in_sizes[6];
    int nb = (J + TPB - 1) / TPB;

    // workspace layout
    char* wsp = (char*)d_ws;
    int* bsum = (int*)wsp;
    wsp += (((size_t)nb * 4) + 255) / 256 * 256;
    int* jsv = (int*)wsp;
    wsp += (((size_t)J * 4) + 255) / 256 * 256;
    uint4* wfrag = (uint4*)wsp;            // 20*64*16 B
    wsp += 20 * 64 * 16;
    float4* bfrag = (float4*)wsp;          // 3*64*16 B
    wsp += 3 * 64 * 16;
    unsigned* s16 = (unsigned*)wsp;        // [4][J][16 f16] = J*128 bytes

    k_prep<<<4 * nb + 1, TPB, 0, stream>>>(x, h_dag, h_glob, ptr, job_indices, num_exec_acts,
                                           J, nb, s16, bsum, jsv,
                                           W1, b1, W2, b2, W3, b3, W4, wfrag, bfrag);

    int numTiles = (T + 127) / 128;
    int grid = numTiles < 2048 ? numTiles : 2048;
    int chunk = (numTiles + grid - 1) / grid;
    grid = (numTiles + chunk - 1) / chunk;
    k_mlp_mfma<<<grid, TPB, 0, stream>>>(s16, W1, jsv, bsum, wfrag, bfrag, b4,
                                         out, T, J, nb, numTiles, chunk);
}